// Round 15
// baseline (651.325 us; speedup 1.0000x reference)
//
#include <hip/hip_runtime.h>
#include <math.h>

#define Bn 128
#define Nn 512
#define Cc 7
#define Hh 64
#define Kk 16
#define Rr 2
#define EPSf 1e-5f

typedef __attribute__((ext_vector_type(8))) short bf16x8;
typedef __attribute__((ext_vector_type(4))) float f32x4;

#define PLN ((size_t)4194304)   // elements per h-split plane (B*N*H)

// exact truncation split: a = hi + mid + lo + r, |r| <= 2^-24 |a|
__device__ __forceinline__ void split3(float a, short &hs, short &ms, short &ls) {
    unsigned u  = __float_as_uint(a);
    unsigned hu = u & 0xFFFF0000u;
    float r1 = a - __uint_as_float(hu);
    unsigned mu = __float_as_uint(r1) & 0xFFFF0000u;
    float r2 = r1 - __uint_as_float(mu);
    unsigned lu = __float_as_uint(r2) & 0xFFFF0000u;
    hs = (short)(hu >> 16); ms = (short)(mu >> 16); ls = (short)(lu >> 16);
}

#define MFMA6(acc, AH, AM, AL, BH, BM, BL) \
    acc = __builtin_amdgcn_mfma_f32_16x16x32_bf16(AL, BH, acc, 0, 0, 0); \
    acc = __builtin_amdgcn_mfma_f32_16x16x32_bf16(AM, BM, acc, 0, 0, 0); \
    acc = __builtin_amdgcn_mfma_f32_16x16x32_bf16(AH, BL, acc, 0, 0, 0); \
    acc = __builtin_amdgcn_mfma_f32_16x16x32_bf16(AM, BH, acc, 0, 0, 0); \
    acc = __builtin_amdgcn_mfma_f32_16x16x32_bf16(AH, BM, acc, 0, 0, 0); \
    acc = __builtin_amdgcn_mfma_f32_16x16x32_bf16(AH, BH, acc, 0, 0, 0);

// ---------------------------------------------------------------------------
// prep: split weights into bf16x3 planes.
// wS layout (4096-short planes): [r0: wd x3, wcd x3][r1: wd x3, wcd x3]
//                                [w_t2 x3][w_s1 x3]   (18 planes total)
// ---------------------------------------------------------------------------
__global__ void k_prep(const float* __restrict__ w_nb, const float* __restrict__ w_t2,
                       const float* __restrict__ w_s1, short* __restrict__ wS)
{
    int i = blockIdx.x * 256 + threadIdx.x;     // 0 .. 16383
    short h_, m_, l_;
    if (i < 8192) {
        int r = i >> 12, oc = i & 4095;
        int o = oc >> 6, c = oc & 63;
        const float* wr = w_nb + (size_t)r * Hh * 2 * Hh + (size_t)o * 2 * Hh;
        float wc = wr[c], wd = wr[Hh + c];
        short* base = wS + (size_t)r * 6 * 4096;
        split3(wd, h_, m_, l_);
        base[0 * 4096 + oc] = h_; base[1 * 4096 + oc] = m_; base[2 * 4096 + oc] = l_;
        split3(wc - wd, h_, m_, l_);
        base[3 * 4096 + oc] = h_; base[4 * 4096 + oc] = m_; base[5 * 4096 + oc] = l_;
    } else {
        int which = (i - 8192) >> 12;            // 0: w_t2, 1: w_s1
        int oc = i & 4095;
        const float* src = which ? w_s1 : w_t2;
        short* base = wS + (size_t)(12 + which * 3) * 4096;
        split3(src[oc], h_, m_, l_);
        base[0 * 4096 + oc] = h_; base[1 * 4096 + oc] = m_; base[2 * 4096 + oc] = l_;
    }
}

// ---------------------------------------------------------------------------
// t1 + t2: layer 1 fp32 VALU (bit-exact), layer 2 via MFMA6 from split planes.
// ---------------------------------------------------------------------------
__global__ __launch_bounds__(256) void k_t12(
    const float* __restrict__ x,
    const float* __restrict__ w1, const float* __restrict__ g1, const float* __restrict__ b1,
    const short* __restrict__ wS2, const float* __restrict__ g2, const float* __restrict__ b2,
    short* __restrict__ hS, float* __restrict__ sq)
{
    __shared__ short wLDS[3][64 * 80];
    __shared__ short h1S[3][16 * 80];
    __shared__ float sqP[16][4];

    int t  = threadIdx.x;
    int p0 = blockIdx.x * 16;
    int b  = p0 >> 9, n0 = p0 & 511;

#pragma unroll
    for (int it = 0; it < 6; ++it) {
        int f = it * 256 + t;
        int plane = f >> 9, i8 = f & 511;
        int o = i8 >> 3, c8 = i8 & 7;
        uint4 v = ((const uint4*)(wS2 + (size_t)plane * 4096))[i8];
        *(uint4*)&wLDS[plane][o * 80 + c8 * 8] = v;
    }

    {
        int pt = t & 15, ow = t >> 4;
        const float inv = rsqrtf(1.0f + EPSf);
        float xv[Cc];
#pragma unroll
        for (int c = 0; c < Cc; ++c)
            xv[c] = x[(b * Cc + c) * Nn + n0 + pt];
#pragma unroll
        for (int j = 0; j < 4; ++j) {
            int o = ow + 16 * j;
            float acc = 0.0f;
#pragma unroll
            for (int c = 0; c < Cc; ++c)
                acc = fmaf(w1[o * Cc + c], xv[c], acc);
            acc = fmaf(acc, g1[o] * inv, b1[o]);
            acc = fmaxf(acc, 0.0f);
            short hs_, ms_, ls_;
            split3(acc, hs_, ms_, ls_);
            h1S[0][pt * 80 + o] = hs_;
            h1S[1][pt * 80 + o] = ms_;
            h1S[2][pt * 80 + o] = ls_;
        }
    }
    __syncthreads();

    int wv = t >> 6, lane = t & 63, col = lane & 15, quad = lane >> 4;
    const float inv = rsqrtf(1.0f + EPSf);

    f32x4 acc = (f32x4){0.f, 0.f, 0.f, 0.f};
#pragma unroll
    for (int ks = 0; ks < 2; ++ks) {
        int aoff = ks * 32 + quad * 8;
        bf16x8 AH = *(bf16x8*)&h1S[0][col * 80 + aoff];
        bf16x8 AM = *(bf16x8*)&h1S[1][col * 80 + aoff];
        bf16x8 AL = *(bf16x8*)&h1S[2][col * 80 + aoff];
        int boff = (wv * 16 + col) * 80 + aoff;
        bf16x8 BH = *(bf16x8*)&wLDS[0][boff];
        bf16x8 BM = *(bf16x8*)&wLDS[1][boff];
        bf16x8 BL = *(bf16x8*)&wLDS[2][boff];
        MFMA6(acc, AH, AM, AL, BH, BM, BL)
    }

    int o = wv * 16 + col;
    float sc = g2[o] * inv, bo = b2[o];
    float s4[4];
#pragma unroll
    for (int r = 0; r < 4; ++r) {
        int pt = quad * 4 + r;
        float a2 = fmaf(acc[r], sc, bo);
        a2 = fmaxf(a2, 0.0f);
        short hs_, ms_, ls_;
        split3(a2, hs_, ms_, ls_);
        size_t rowp = (size_t)(p0 + pt) * Hh + o;
        hS[0 * PLN + rowp] = hs_;
        hS[1 * PLN + rowp] = ms_;
        hS[2 * PLN + rowp] = ls_;
        s4[r] = a2 * a2;
    }
#pragma unroll
    for (int sh = 1; sh < 16; sh <<= 1) {
#pragma unroll
        for (int r = 0; r < 4; ++r) s4[r] += __shfl_xor(s4[r], sh, 64);
    }
    if (col == 0) {
#pragma unroll
        for (int r = 0; r < 4; ++r) sqP[quad * 4 + r][wv] = s4[r];
    }
    __syncthreads();
    if (t < 16) sq[p0 + t] = sqP[t][0] + sqP[t][1] + sqP[t][2] + sqP[t][3];
}

// ---------------------------------------------------------------------------
// kNN: Gram via MFMA + XCD swizzle. 8 centers/block, keysLDS 16 KB.
// __launch_bounds__(256,4): R14's (256,8) forced a 32-VGPR cap -> spills
// (VGPR_Count=32, VALUBusy 45%, 218us). With the 128-VGPR cap the compiler
// picks 64 VGPR (R12/R13 evidence) and BOTH the 18.4 KB LDS and 64-VGPR
// budgets allow 8 blocks/CU -> high occupancy without spills.
// Keys/sort/tie-break identical -> bit-identical indices.
// ---------------------------------------------------------------------------
__global__ __launch_bounds__(256, 4) void k_knn(
    const short* __restrict__ hS, const float* __restrict__ sq, int* __restrict__ idxout)
{
    int xcd = blockIdx.x & 7;
    int s_  = blockIdx.x >> 3;             // 0..1023
    int b   = xcd + ((s_ >> 6) << 3);      // batch, b%8 == xcd
    int n0  = (s_ & 63) << 3;              // 8 centers
    int t   = threadIdx.x;

    __shared__ unsigned int keysLDS[8 * 512];    // 16 KB
    __shared__ float sqS[512];

    if (t < 128) ((float4*)sqS)[t] = ((const float4*)(sq + (size_t)b * Nn))[t];
    __syncthreads();

    int wv = t >> 6, lane = t & 63, col = lane & 15, quad = lane >> 4;
    const size_t rowbase = (size_t)b * Nn * Hh;

    // A-frags: 8 center rows, duplicated into rows 8-15 (outputs discarded)
    bf16x8 AH[2], AM[2], AL[2];
    {
        const short* crow = hS + rowbase + (size_t)(n0 + (col & 7)) * Hh;
#pragma unroll
        for (int ks = 0; ks < 2; ++ks) {
            int aoff = ks * 32 + quad * 8;
            AH[ks] = *(const bf16x8*)(crow + 0 * PLN + aoff);
            AM[ks] = *(const bf16x8*)(crow + 1 * PLN + aoff);
            AL[ks] = *(const bf16x8*)(crow + 2 * PLN + aoff);
        }
    }
    float sqcr[4];
#pragma unroll
    for (int r_ = 0; r_ < 4; ++r_)
        sqcr[r_] = sqS[n0 + ((quad * 4 + r_) & 7)];

#pragma unroll
    for (int i = 0; i < 8; ++i) {
        int nt = wv * 8 + i;
        const short* prow = hS + rowbase + (size_t)(nt * 16 + col) * Hh;
        f32x4 acc = (f32x4){0.f, 0.f, 0.f, 0.f};
#pragma unroll
        for (int ks = 0; ks < 2; ++ks) {
            int aoff = ks * 32 + quad * 8;
            bf16x8 BH = *(const bf16x8*)(prow + 0 * PLN + aoff);
            bf16x8 BM = *(const bf16x8*)(prow + 1 * PLN + aoff);
            bf16x8 BL = *(const bf16x8*)(prow + 2 * PLN + aoff);
            MFMA6(acc, AH[ks], AM[ks], AL[ks], BH, BM, BL)
        }
        float sqp = sqS[nt * 16 + col];
        if (quad < 2) {
#pragma unroll
            for (int r_ = 0; r_ < 4; ++r_) {
                int ctr = quad * 4 + r_;         // 0..7
                float d = sqcr[r_] + sqp - 2.0f * acc[r_];
                unsigned int u = __float_as_uint(d);
                u = ((int)u < 0) ? ~u : (u | 0x80000000u);
                keysLDS[ctr * 512 + nt * 16 + col] = u;
            }
        }
    }
    __syncthreads();

    // selection: wave wv handles centers jj = wv*2, wv*2+1 concurrently
    unsigned int kk[2][8];
    int rr[2][8];
#pragma unroll
    for (int s = 0; s < 2; ++s) {
        int jj = wv * 2 + s;
        const uint4* kp = (const uint4*)&keysLDS[jj * 512 + (lane << 3)];
        uint4 A = kp[0], Bq = kp[1];
        kk[s][0] = A.x;  kk[s][1] = A.y;  kk[s][2] = A.z;  kk[s][3] = A.w;
        kk[s][4] = Bq.x; kk[s][5] = Bq.y; kk[s][6] = Bq.z; kk[s][7] = Bq.w;
#pragma unroll
        for (int q = 0; q < 8; ++q) rr[s][q] = q;
    }

#define CE(s, i, j_) { \
    bool sw = (kk[s][i] > kk[s][j_]) || (kk[s][i] == kk[s][j_] && rr[s][i] > rr[s][j_]); \
    unsigned int tk = sw ? kk[s][i] : kk[s][j_]; kk[s][i] = sw ? kk[s][j_] : kk[s][i]; kk[s][j_] = tk; \
    int tr = sw ? rr[s][i] : rr[s][j_]; rr[s][i] = sw ? rr[s][j_] : rr[s][i]; rr[s][j_] = tr; }
#pragma unroll
    for (int s = 0; s < 2; ++s) {
        CE(s,0,1) CE(s,2,3) CE(s,4,5) CE(s,6,7)
        CE(s,0,2) CE(s,1,3) CE(s,4,6) CE(s,5,7)
        CE(s,1,2) CE(s,5,6)
        CE(s,0,4) CE(s,1,5) CE(s,2,6) CE(s,3,7)
        CE(s,2,4) CE(s,3,5)
        CE(s,1,2) CE(s,3,4) CE(s,5,6)
    }
#undef CE

    int outbase[2];
#pragma unroll
    for (int s = 0; s < 2; ++s)
        outbase[s] = (b * Nn + n0 + wv * 2 + s) * Kk;

    for (int iter = 0; iter < Kk; ++iter) {
        unsigned int mv[2];
#pragma unroll
        for (int s = 0; s < 2; ++s) mv[s] = kk[s][0];
        // pure-DPP 64-lane min all-reduce; full min lands in lane 63
#define DSTEP(ctrl) { \
        _Pragma("unroll") \
        for (int s = 0; s < 2; ++s) { \
            unsigned int ov = (unsigned int)__builtin_amdgcn_update_dpp((int)mv[s], (int)mv[s], ctrl, 0xF, 0xF, false); \
            mv[s] = (ov < mv[s]) ? ov : mv[s]; } }
        DSTEP(0xB1)    // quad_perm xor1
        DSTEP(0x4E)    // quad_perm xor2
        DSTEP(0x124)   // row_ror:4
        DSTEP(0x128)   // row_ror:8     -> each row16 uniform
        DSTEP(0x142)   // row_bcast15
        DSTEP(0x143)   // row_bcast31   -> lane63 holds full min
#undef DSTEP
        unsigned int m[2];
#pragma unroll
        for (int s = 0; s < 2; ++s)
            m[s] = (unsigned int)__builtin_amdgcn_readlane((int)mv[s], 63);
#pragma unroll
        for (int s = 0; s < 2; ++s) {
            unsigned long long bal = __ballot(kk[s][0] == m[s]);
            int wn = __ffsll(bal) - 1;
            if (lane == wn) {
                idxout[outbase[s] + iter] = (lane << 3) + rr[s][0];
#pragma unroll
                for (int q = 0; q < 7; ++q) { kk[s][q] = kk[s][q + 1]; rr[s][q] = rr[s][q + 1]; }
                kk[s][7] = 0xFFFFFFFFu;
            }
        }
    }
}

// ---------------------------------------------------------------------------
// EdgeConv via MFMA, base/delta, XCD swizzle (unchanged)
// ---------------------------------------------------------------------------
__global__ __launch_bounds__(256, 4) void k_edge(
    const short* __restrict__ hS,
    const int* __restrict__ idx,
    const short* __restrict__ wS,
    const float* __restrict__ g, const float* __restrict__ bb_,
    short* __restrict__ hSout, float* __restrict__ sqout)
{
    __shared__ short wLDS[3][64 * 72];
    __shared__ float baseS[16 * 68];
    __shared__ int   idxS[256];

    int t   = threadIdx.x;
    int xcd = blockIdx.x & 7;
    int s_  = blockIdx.x >> 3;
    int b   = xcd + ((s_ >> 5) << 3);
    int p0  = b * Nn + ((s_ & 31) << 4);

    idxS[t] = idx[p0 * Kk + t];
#pragma unroll
    for (int it = 0; it < 6; ++it) {
        int f = it * 256 + t;
        int plane = f >> 9;
        int i8 = f & 511;
        int o = i8 >> 3, c8 = i8 & 7;
        uint4 v = ((const uint4*)(wS + (size_t)(3 + plane) * 4096))[i8];
        *(uint4*)&wLDS[plane][o * 72 + c8 * 8] = v;
    }
    __syncthreads();

    int wv = t >> 6, lane = t & 63, col = lane & 15, quad = lane >> 4;

    {
        f32x4 bacc = (f32x4){0.f, 0.f, 0.f, 0.f};
        const short* hrow = hS + (size_t)(p0 + col) * Hh;
#pragma unroll
        for (int ks = 0; ks < 2; ++ks) {
            int aoff = ks * 32 + quad * 8;
            bf16x8 AH = *(const bf16x8*)(hrow + 0 * PLN + aoff);
            bf16x8 AM = *(const bf16x8*)(hrow + 1 * PLN + aoff);
            bf16x8 AL = *(const bf16x8*)(hrow + 2 * PLN + aoff);
            int boff = (wv * 16 + col) * 72 + aoff;
            bf16x8 BH = *(bf16x8*)&wLDS[0][boff];
            bf16x8 BM = *(bf16x8*)&wLDS[1][boff];
            bf16x8 BL = *(bf16x8*)&wLDS[2][boff];
            MFMA6(bacc, AH, AM, AL, BH, BM, BL)
        }
#pragma unroll
        for (int r_ = 0; r_ < 4; ++r_)
            baseS[(quad * 4 + r_) * 68 + wv * 16 + col] = bacc[r_];
    }
    __syncthreads();

#pragma unroll
    for (int it = 0; it < 6; ++it) {
        int f = it * 256 + t;
        int plane = f >> 9;
        int i8 = f & 511;
        int o = i8 >> 3, c8 = i8 & 7;
        uint4 v = ((const uint4*)(wS + (size_t)plane * 4096))[i8];
        *(uint4*)&wLDS[plane][o * 72 + c8 * 8] = v;
    }
    __syncthreads();

    const float inv = rsqrtf(1.0f + EPSf);
    float scv[4], bov[4];
#pragma unroll
    for (int nt = 0; nt < 4; ++nt) {
        scv[nt] = g[nt * 16 + col] * inv;
        bov[nt] = bb_[nt * 16 + col];
    }

    for (int pr = 0; pr < 2; ++pr) {
        bf16x8 A[2][2][3];
#pragma unroll
        for (int pt2 = 0; pt2 < 2; ++pt2) {
            int pl = wv * 4 + pr * 2 + pt2;
            int j = idxS[pl * 16 + col];
            const short* nrow = hS + ((size_t)(b * Nn) + j) * Hh;
#pragma unroll
            for (int ks = 0; ks < 2; ++ks) {
                int aoff = ks * 32 + quad * 8;
                A[pt2][ks][0] = *(const bf16x8*)(nrow + 0 * PLN + aoff);
                A[pt2][ks][1] = *(const bf16x8*)(nrow + 1 * PLN + aoff);
                A[pt2][ks][2] = *(const bf16x8*)(nrow + 2 * PLN + aoff);
            }
        }

        f32x4 acc[2][4];
#pragma unroll
        for (int pt2 = 0; pt2 < 2; ++pt2)
#pragma unroll
            for (int nt = 0; nt < 4; ++nt)
                acc[pt2][nt] = (f32x4){0.f, 0.f, 0.f, 0.f};

#pragma unroll
        for (int ks = 0; ks < 2; ++ks)
#pragma unroll
            for (int nt = 0; nt < 4; ++nt) {
                int boff = (nt * 16 + col) * 72 + ks * 32 + quad * 8;
                bf16x8 BH = *(bf16x8*)&wLDS[0][boff];
                bf16x8 BM = *(bf16x8*)&wLDS[1][boff];
                bf16x8 BL = *(bf16x8*)&wLDS[2][boff];
#pragma unroll
                for (int pt2 = 0; pt2 < 2; ++pt2) {
                    f32x4 a = acc[pt2][nt];
                    MFMA6(a, A[pt2][ks][0], A[pt2][ks][1], A[pt2][ks][2], BH, BM, BL)
                    acc[pt2][nt] = a;
                }
            }

#pragma unroll
        for (int pt2 = 0; pt2 < 2; ++pt2) {
            int pl = wv * 4 + pr * 2 + pt2;
            int pglob = p0 + pl;
            float res[4];
#pragma unroll
            for (int nt = 0; nt < 4; ++nt) {
                float base = baseS[pl * 68 + nt * 16 + col];
                f32x4 a = acc[pt2][nt];
                float v0 = fmaf(base + a[0], scv[nt], bov[nt]);
                float v1 = fmaf(base + a[1], scv[nt], bov[nt]);
                float v2 = fmaf(base + a[2], scv[nt], bov[nt]);
                float v3 = fmaf(base + a[3], scv[nt], bov[nt]);
                float vm = fmaxf(fmaxf(v0, v1), fmaxf(v2, v3));
                vm = fmaxf(vm, __shfl_xor(vm, 16));
                vm = fmaxf(vm, __shfl_xor(vm, 32));
                res[nt] = fmaxf(vm, 0.0f);
            }
            float rv = res[quad];
            short hs_, ms_, ls_;
            split3(rv, hs_, ms_, ls_);
            hSout[0 * PLN + (size_t)pglob * Hh + lane] = hs_;
            hSout[1 * PLN + (size_t)pglob * Hh + lane] = ms_;
            hSout[2 * PLN + (size_t)pglob * Hh + lane] = ls_;

            float s = res[0] * res[0] + res[1] * res[1]
                    + res[2] * res[2] + res[3] * res[3];
            s += __shfl_xor(s, 1);
            s += __shfl_xor(s, 2);
            s += __shfl_xor(s, 4);
            s += __shfl_xor(s, 8);
            if (lane == 0) sqout[pglob] = s;
        }
    }
}

// ---------------------------------------------------------------------------
// head via MFMA (unchanged)
// ---------------------------------------------------------------------------
__global__ __launch_bounds__(256) void k_head(
    const short* __restrict__ hS, const short* __restrict__ wSs1,
    const float* __restrict__ g1, const float* __restrict__ b1,
    const float* __restrict__ w2, const float* __restrict__ b2,
    float* __restrict__ out)
{
    __shared__ short wLDS[3][64 * 80];
    __shared__ float partS[16][4];

    int t  = threadIdx.x;
    int p0 = blockIdx.x * 16;

#pragma unroll
    for (int it = 0; it < 6; ++it) {
        int f = it * 256 + t;
        int plane = f >> 9, i8 = f & 511;
        int o = i8 >> 3, c8 = i8 & 7;
        uint4 v = ((const uint4*)(wSs1 + (size_t)plane * 4096))[i8];
        *(uint4*)&wLDS[plane][o * 80 + c8 * 8] = v;
    }
    __syncthreads();

    int wv = t >> 6, lane = t & 63, col = lane & 15, quad = lane >> 4;

    const short* crow = hS + (size_t)(p0 + col) * Hh;
    f32x4 acc = (f32x4){0.f, 0.f, 0.f, 0.f};
#pragma unroll
    for (int ks = 0; ks < 2; ++ks) {
        int aoff = ks * 32 + quad * 8;
        bf16x8 AH = *(const bf16x8*)(crow + 0 * PLN + aoff);
        bf16x8 AM = *(const bf16x8*)(crow + 1 * PLN + aoff);
        bf16x8 AL = *(const bf16x8*)(crow + 2 * PLN + aoff);
        int boff = (wv * 16 + col) * 80 + aoff;
        bf16x8 BH = *(bf16x8*)&wLDS[0][boff];
        bf16x8 BM = *(bf16x8*)&wLDS[1][boff];
        bf16x8 BL = *(bf16x8*)&wLDS[2][boff];
        MFMA6(acc, AH, AM, AL, BH, BM, BL)
    }

    int o = wv * 16 + col;
    const float inv = rsqrtf(1.0f + EPSf);
    float sc = g1[o] * inv, bo = b1[o], w2o = w2[o];
    float s4[4];
#pragma unroll
    for (int r = 0; r < 4; ++r) {
        float a = fmaxf(fmaf(acc[r], sc, bo), 0.0f);
        s4[r] = a * w2o;
    }
#pragma unroll
    for (int sh = 1; sh < 16; sh <<= 1) {
#pragma unroll
        for (int r = 0; r < 4; ++r) s4[r] += __shfl_xor(s4[r], sh, 64);
    }
    if (col == 0) {
#pragma unroll
        for (int r = 0; r < 4; ++r) partS[quad * 4 + r][wv] = s4[r];
    }
    __syncthreads();
    if (t < 16)
        out[p0 + t] = partS[t][0] + partS[t][1] + partS[t][2] + partS[t][3] + b2[0];
}

// ---------------------------------------------------------------------------
extern "C" void kernel_launch(void* const* d_in, const int* in_sizes, int n_in,
                              void* d_out, int out_size, void* d_ws, size_t ws_size,
                              hipStream_t stream)
{
    const float* x    = (const float*)d_in[0];
    const float* w_t1 = (const float*)d_in[1];
    const float* g_t1 = (const float*)d_in[2];
    const float* b_t1 = (const float*)d_in[3];
    const float* w_t2 = (const float*)d_in[4];
    const float* g_t2 = (const float*)d_in[5];
    const float* b_t2 = (const float*)d_in[6];
    const float* w_nb = (const float*)d_in[7];
    const float* g_nb = (const float*)d_in[8];
    const float* b_nb = (const float*)d_in[9];
    const float* w_s1 = (const float*)d_in[10];
    const float* g_s1 = (const float*)d_in[11];
    const float* b_s1 = (const float*)d_in[12];
    const float* w_s2 = (const float*)d_in[13];
    const float* b_s2 = (const float*)d_in[14];
    float* out = (float*)d_out;

    float* sq  = (float*)d_ws;
    int*   idx = (int*)(sq + (size_t)Bn * Nn);
    short* hSa = (short*)(idx + (size_t)Bn * Nn * Kk);
    short* hSb = hSa + 3 * PLN;
    short* wS  = hSb + 3 * PLN;            // 18 planes x 4096 shorts

    k_prep<<<64, 256, 0, stream>>>(w_nb, w_t2, w_s1, wS);
    k_t12<<<Bn * Nn / 16, 256, 0, stream>>>(x, w_t1, g_t1, b_t1,
                                            wS + (size_t)12 * 4096, g_t2, b_t2,
                                            hSa, sq);

    const short* hSin = hSa;
    short* hSout = hSb;
    for (int r = 0; r < Rr; ++r) {
        k_knn<<<Bn * (Nn / 8), 256, 0, stream>>>(hSin, sq, idx);
        k_edge<<<Bn * Nn / 16, 256, 0, stream>>>(hSin, idx,
            wS + (size_t)r * 6 * 4096, g_nb + r * Hh, b_nb + r * Hh,
            hSout, sq);
        const short* ts = hSout; hSout = (short*)hSin; hSin = ts;
    }
    k_head<<<Bn * Nn / 16, 256, 0, stream>>>(hSin, wS + (size_t)15 * 4096,
                                             g_s1, b_s1, w_s2, b_s2, out);
}

// Round 16
// 545.159 us; speedup vs baseline: 1.1947x; 1.1947x over previous
//
#include <hip/hip_runtime.h>
#include <math.h>

#define Bn 128
#define Nn 512
#define Cc 7
#define Hh 64
#define Kk 16
#define Rr 2
#define EPSf 1e-5f

typedef __attribute__((ext_vector_type(8))) short bf16x8;
typedef __attribute__((ext_vector_type(4))) float f32x4;

#define PLN ((size_t)4194304)   // elements per h-split plane (B*N*H)

// exact truncation split: a = hi + mid + lo + r, |r| <= 2^-24 |a|
__device__ __forceinline__ void split3(float a, short &hs, short &ms, short &ls) {
    unsigned u  = __float_as_uint(a);
    unsigned hu = u & 0xFFFF0000u;
    float r1 = a - __uint_as_float(hu);
    unsigned mu = __float_as_uint(r1) & 0xFFFF0000u;
    float r2 = r1 - __uint_as_float(mu);
    unsigned lu = __float_as_uint(r2) & 0xFFFF0000u;
    hs = (short)(hu >> 16); ms = (short)(mu >> 16); ls = (short)(lu >> 16);
}

#define MFMA6(acc, AH, AM, AL, BH, BM, BL) \
    acc = __builtin_amdgcn_mfma_f32_16x16x32_bf16(AL, BH, acc, 0, 0, 0); \
    acc = __builtin_amdgcn_mfma_f32_16x16x32_bf16(AM, BM, acc, 0, 0, 0); \
    acc = __builtin_amdgcn_mfma_f32_16x16x32_bf16(AH, BL, acc, 0, 0, 0); \
    acc = __builtin_amdgcn_mfma_f32_16x16x32_bf16(AM, BH, acc, 0, 0, 0); \
    acc = __builtin_amdgcn_mfma_f32_16x16x32_bf16(AH, BM, acc, 0, 0, 0); \
    acc = __builtin_amdgcn_mfma_f32_16x16x32_bf16(AH, BH, acc, 0, 0, 0);

// ---------------------------------------------------------------------------
// prep: split weights into bf16x3 planes.
// ---------------------------------------------------------------------------
__global__ void k_prep(const float* __restrict__ w_nb, const float* __restrict__ w_t2,
                       const float* __restrict__ w_s1, short* __restrict__ wS)
{
    int i = blockIdx.x * 256 + threadIdx.x;     // 0 .. 16383
    short h_, m_, l_;
    if (i < 8192) {
        int r = i >> 12, oc = i & 4095;
        int o = oc >> 6, c = oc & 63;
        const float* wr = w_nb + (size_t)r * Hh * 2 * Hh + (size_t)o * 2 * Hh;
        float wc = wr[c], wd = wr[Hh + c];
        short* base = wS + (size_t)r * 6 * 4096;
        split3(wd, h_, m_, l_);
        base[0 * 4096 + oc] = h_; base[1 * 4096 + oc] = m_; base[2 * 4096 + oc] = l_;
        split3(wc - wd, h_, m_, l_);
        base[3 * 4096 + oc] = h_; base[4 * 4096 + oc] = m_; base[5 * 4096 + oc] = l_;
    } else {
        int which = (i - 8192) >> 12;            // 0: w_t2, 1: w_s1
        int oc = i & 4095;
        const float* src = which ? w_s1 : w_t2;
        short* base = wS + (size_t)(12 + which * 3) * 4096;
        split3(src[oc], h_, m_, l_);
        base[0 * 4096 + oc] = h_; base[1 * 4096 + oc] = m_; base[2 * 4096 + oc] = l_;
    }
}

// ---------------------------------------------------------------------------
// t1 + t2: layer 1 fp32 VALU (bit-exact), layer 2 via MFMA6 from split planes.
// ---------------------------------------------------------------------------
__global__ __launch_bounds__(256) void k_t12(
    const float* __restrict__ x,
    const float* __restrict__ w1, const float* __restrict__ g1, const float* __restrict__ b1,
    const short* __restrict__ wS2, const float* __restrict__ g2, const float* __restrict__ b2,
    short* __restrict__ hS, float* __restrict__ sq)
{
    __shared__ short wLDS[3][64 * 80];
    __shared__ short h1S[3][16 * 80];
    __shared__ float sqP[16][4];

    int t  = threadIdx.x;
    int p0 = blockIdx.x * 16;
    int b  = p0 >> 9, n0 = p0 & 511;

#pragma unroll
    for (int it = 0; it < 6; ++it) {
        int f = it * 256 + t;
        int plane = f >> 9, i8 = f & 511;
        int o = i8 >> 3, c8 = i8 & 7;
        uint4 v = ((const uint4*)(wS2 + (size_t)plane * 4096))[i8];
        *(uint4*)&wLDS[plane][o * 80 + c8 * 8] = v;
    }

    {
        int pt = t & 15, ow = t >> 4;
        const float inv = rsqrtf(1.0f + EPSf);
        float xv[Cc];
#pragma unroll
        for (int c = 0; c < Cc; ++c)
            xv[c] = x[(b * Cc + c) * Nn + n0 + pt];
#pragma unroll
        for (int j = 0; j < 4; ++j) {
            int o = ow + 16 * j;
            float acc = 0.0f;
#pragma unroll
            for (int c = 0; c < Cc; ++c)
                acc = fmaf(w1[o * Cc + c], xv[c], acc);
            acc = fmaf(acc, g1[o] * inv, b1[o]);
            acc = fmaxf(acc, 0.0f);
            short hs_, ms_, ls_;
            split3(acc, hs_, ms_, ls_);
            h1S[0][pt * 80 + o] = hs_;
            h1S[1][pt * 80 + o] = ms_;
            h1S[2][pt * 80 + o] = ls_;
        }
    }
    __syncthreads();

    int wv = t >> 6, lane = t & 63, col = lane & 15, quad = lane >> 4;
    const float inv = rsqrtf(1.0f + EPSf);

    f32x4 acc = (f32x4){0.f, 0.f, 0.f, 0.f};
#pragma unroll
    for (int ks = 0; ks < 2; ++ks) {
        int aoff = ks * 32 + quad * 8;
        bf16x8 AH = *(bf16x8*)&h1S[0][col * 80 + aoff];
        bf16x8 AM = *(bf16x8*)&h1S[1][col * 80 + aoff];
        bf16x8 AL = *(bf16x8*)&h1S[2][col * 80 + aoff];
        int boff = (wv * 16 + col) * 80 + aoff;
        bf16x8 BH = *(bf16x8*)&wLDS[0][boff];
        bf16x8 BM = *(bf16x8*)&wLDS[1][boff];
        bf16x8 BL = *(bf16x8*)&wLDS[2][boff];
        MFMA6(acc, AH, AM, AL, BH, BM, BL)
    }

    int o = wv * 16 + col;
    float sc = g2[o] * inv, bo = b2[o];
    float s4[4];
#pragma unroll
    for (int r = 0; r < 4; ++r) {
        int pt = quad * 4 + r;
        float a2 = fmaf(acc[r], sc, bo);
        a2 = fmaxf(a2, 0.0f);
        short hs_, ms_, ls_;
        split3(a2, hs_, ms_, ls_);
        size_t rowp = (size_t)(p0 + pt) * Hh + o;
        hS[0 * PLN + rowp] = hs_;
        hS[1 * PLN + rowp] = ms_;
        hS[2 * PLN + rowp] = ls_;
        s4[r] = a2 * a2;
    }
#pragma unroll
    for (int sh = 1; sh < 16; sh <<= 1) {
#pragma unroll
        for (int r = 0; r < 4; ++r) s4[r] += __shfl_xor(s4[r], sh, 64);
    }
    if (col == 0) {
#pragma unroll
        for (int r = 0; r < 4; ++r) sqP[quad * 4 + r][wv] = s4[r];
    }
    __syncthreads();
    if (t < 16) sq[p0 + t] = sqP[t][0] + sqP[t][1] + sqP[t][2] + sqP[t][3];
}

// ---------------------------------------------------------------------------
// Gram phase: MFMA distance keys -> GLOBAL keysG (no keysLDS; only 2 KB LDS).
// Same key values as R13 (bit-identical).
// ---------------------------------------------------------------------------
__global__ __launch_bounds__(256) void k_gram(
    const short* __restrict__ hS, const float* __restrict__ sq,
    unsigned int* __restrict__ keysG)
{
    int xcd = blockIdx.x & 7;
    int s_  = blockIdx.x >> 3;             // 0..511
    int b   = xcd + ((s_ >> 5) << 3);      // batch, b%8 == xcd
    int n0  = (s_ & 31) << 4;              // 16 centers
    int t   = threadIdx.x;

    __shared__ float sqS[512];
    if (t < 128) ((float4*)sqS)[t] = ((const float4*)(sq + (size_t)b * Nn))[t];
    __syncthreads();

    int wv = t >> 6, lane = t & 63, col = lane & 15, quad = lane >> 4;
    const size_t rowbase = (size_t)b * Nn * Hh;

    bf16x8 AH[2], AM[2], AL[2];
    {
        const short* crow = hS + rowbase + (size_t)(n0 + col) * Hh;
#pragma unroll
        for (int ks = 0; ks < 2; ++ks) {
            int aoff = ks * 32 + quad * 8;
            AH[ks] = *(const bf16x8*)(crow + 0 * PLN + aoff);
            AM[ks] = *(const bf16x8*)(crow + 1 * PLN + aoff);
            AL[ks] = *(const bf16x8*)(crow + 2 * PLN + aoff);
        }
    }
    float sqcr[4];
#pragma unroll
    for (int r_ = 0; r_ < 4; ++r_) sqcr[r_] = sqS[n0 + quad * 4 + r_];

    unsigned int* kout = keysG + ((size_t)b * Nn + n0) * Nn;

    for (int i = 0; i < 8; ++i) {
        int nt = wv * 8 + i;
        const short* prow = hS + rowbase + (size_t)(nt * 16 + col) * Hh;
        f32x4 acc = (f32x4){0.f, 0.f, 0.f, 0.f};
#pragma unroll
        for (int ks = 0; ks < 2; ++ks) {
            int aoff = ks * 32 + quad * 8;
            bf16x8 BH = *(const bf16x8*)(prow + 0 * PLN + aoff);
            bf16x8 BM = *(const bf16x8*)(prow + 1 * PLN + aoff);
            bf16x8 BL = *(const bf16x8*)(prow + 2 * PLN + aoff);
            MFMA6(acc, AH[ks], AM[ks], AL[ks], BH, BM, BL)
        }
        float sqp = sqS[nt * 16 + col];
#pragma unroll
        for (int r_ = 0; r_ < 4; ++r_) {
            int ctr = quad * 4 + r_;
            float d = sqcr[r_] + sqp - 2.0f * acc[r_];
            unsigned int u = __float_as_uint(d);
            u = ((int)u < 0) ? ~u : (u | 0x80000000u);
            kout[(size_t)ctr * Nn + nt * 16 + col] = u;
        }
    }
}

// ---------------------------------------------------------------------------
// Selection phase: ZERO LDS, one center per wave (state ~30 VGPRs — fits the
// 32-arch-VGPR allocation even at 8 waves/SIMD, no acc-churn). Keys from
// global (L3/L2-hot, writer on same XCD). Sort-8 + DPP tournament +
// ballot-ffs lane-major tie-break — byte-identical logic to R13 ->
// bit-identical indices.
// ---------------------------------------------------------------------------
__global__ __launch_bounds__(256) void k_sel(
    const unsigned int* __restrict__ keysG, int* __restrict__ idxout)
{
    int xcd = blockIdx.x & 7;
    int s_  = blockIdx.x >> 3;             // 0..2047
    int b   = xcd + ((s_ >> 7) << 3);      // batch, b%8 == xcd
    int n0  = (s_ & 127) << 2;             // 4 centers per block
    int t   = threadIdx.x;
    int wv  = t >> 6, lane = t & 63;
    int jj  = n0 + wv;                     // this wave's center

    unsigned int kk[8];
    int rr[8];
    {
        const uint4* kp = (const uint4*)(keysG + ((size_t)b * Nn + jj) * Nn + (lane << 3));
        uint4 A = kp[0], Bq = kp[1];
        kk[0] = A.x;  kk[1] = A.y;  kk[2] = A.z;  kk[3] = A.w;
        kk[4] = Bq.x; kk[5] = Bq.y; kk[6] = Bq.z; kk[7] = Bq.w;
#pragma unroll
        for (int q = 0; q < 8; ++q) rr[q] = q;
    }

#define CE(i, j_) { \
    bool sw = (kk[i] > kk[j_]) || (kk[i] == kk[j_] && rr[i] > rr[j_]); \
    unsigned int tk = sw ? kk[i] : kk[j_]; kk[i] = sw ? kk[j_] : kk[i]; kk[j_] = tk; \
    int tr = sw ? rr[i] : rr[j_]; rr[i] = sw ? rr[j_] : rr[i]; rr[j_] = tr; }
    CE(0,1) CE(2,3) CE(4,5) CE(6,7)
    CE(0,2) CE(1,3) CE(4,6) CE(5,7)
    CE(1,2) CE(5,6)
    CE(0,4) CE(1,5) CE(2,6) CE(3,7)
    CE(2,4) CE(3,5)
    CE(1,2) CE(3,4) CE(5,6)
#undef CE

    int outbase = (b * Nn + jj) * Kk;

    for (int iter = 0; iter < Kk; ++iter) {
        unsigned int mv = kk[0];
        // pure-DPP 64-lane min all-reduce; full min lands in lane 63
#define DSTEP(ctrl) { \
        unsigned int ov = (unsigned int)__builtin_amdgcn_update_dpp((int)mv, (int)mv, ctrl, 0xF, 0xF, false); \
        mv = (ov < mv) ? ov : mv; }
        DSTEP(0xB1)    // quad_perm xor1
        DSTEP(0x4E)    // quad_perm xor2
        DSTEP(0x124)   // row_ror:4
        DSTEP(0x128)   // row_ror:8     -> each row16 uniform
        DSTEP(0x142)   // row_bcast15
        DSTEP(0x143)   // row_bcast31   -> lane63 holds full min
#undef DSTEP
        unsigned int m = (unsigned int)__builtin_amdgcn_readlane((int)mv, 63);
        unsigned long long bal = __ballot(kk[0] == m);
        int wn = __ffsll(bal) - 1;
        if (lane == wn) {
            idxout[outbase + iter] = (lane << 3) + rr[0];
#pragma unroll
            for (int q = 0; q < 7; ++q) { kk[q] = kk[q + 1]; rr[q] = rr[q + 1]; }
            kk[7] = 0xFFFFFFFFu;
        }
    }
}

// ---------------------------------------------------------------------------
// EdgeConv via MFMA, base/delta, XCD swizzle (unchanged from R13)
// ---------------------------------------------------------------------------
__global__ __launch_bounds__(256, 4) void k_edge(
    const short* __restrict__ hS,
    const int* __restrict__ idx,
    const short* __restrict__ wS,
    const float* __restrict__ g, const float* __restrict__ bb_,
    short* __restrict__ hSout, float* __restrict__ sqout)
{
    __shared__ short wLDS[3][64 * 72];
    __shared__ float baseS[16 * 68];
    __shared__ int   idxS[256];

    int t   = threadIdx.x;
    int xcd = blockIdx.x & 7;
    int s_  = blockIdx.x >> 3;
    int b   = xcd + ((s_ >> 5) << 3);
    int p0  = b * Nn + ((s_ & 31) << 4);

    idxS[t] = idx[p0 * Kk + t];
#pragma unroll
    for (int it = 0; it < 6; ++it) {
        int f = it * 256 + t;
        int plane = f >> 9;
        int i8 = f & 511;
        int o = i8 >> 3, c8 = i8 & 7;
        uint4 v = ((const uint4*)(wS + (size_t)(3 + plane) * 4096))[i8];
        *(uint4*)&wLDS[plane][o * 72 + c8 * 8] = v;
    }
    __syncthreads();

    int wv = t >> 6, lane = t & 63, col = lane & 15, quad = lane >> 4;

    {
        f32x4 bacc = (f32x4){0.f, 0.f, 0.f, 0.f};
        const short* hrow = hS + (size_t)(p0 + col) * Hh;
#pragma unroll
        for (int ks = 0; ks < 2; ++ks) {
            int aoff = ks * 32 + quad * 8;
            bf16x8 AH = *(const bf16x8*)(hrow + 0 * PLN + aoff);
            bf16x8 AM = *(const bf16x8*)(hrow + 1 * PLN + aoff);
            bf16x8 AL = *(const bf16x8*)(hrow + 2 * PLN + aoff);
            int boff = (wv * 16 + col) * 72 + aoff;
            bf16x8 BH = *(bf16x8*)&wLDS[0][boff];
            bf16x8 BM = *(bf16x8*)&wLDS[1][boff];
            bf16x8 BL = *(bf16x8*)&wLDS[2][boff];
            MFMA6(bacc, AH, AM, AL, BH, BM, BL)
        }
#pragma unroll
        for (int r_ = 0; r_ < 4; ++r_)
            baseS[(quad * 4 + r_) * 68 + wv * 16 + col] = bacc[r_];
    }
    __syncthreads();

#pragma unroll
    for (int it = 0; it < 6; ++it) {
        int f = it * 256 + t;
        int plane = f >> 9;
        int i8 = f & 511;
        int o = i8 >> 3, c8 = i8 & 7;
        uint4 v = ((const uint4*)(wS + (size_t)plane * 4096))[i8];
        *(uint4*)&wLDS[plane][o * 72 + c8 * 8] = v;
    }
    __syncthreads();

    const float inv = rsqrtf(1.0f + EPSf);
    float scv[4], bov[4];
#pragma unroll
    for (int nt = 0; nt < 4; ++nt) {
        scv[nt] = g[nt * 16 + col] * inv;
        bov[nt] = bb_[nt * 16 + col];
    }

    for (int pr = 0; pr < 2; ++pr) {
        bf16x8 A[2][2][3];
#pragma unroll
        for (int pt2 = 0; pt2 < 2; ++pt2) {
            int pl = wv * 4 + pr * 2 + pt2;
            int j = idxS[pl * 16 + col];
            const short* nrow = hS + ((size_t)(b * Nn) + j) * Hh;
#pragma unroll
            for (int ks = 0; ks < 2; ++ks) {
                int aoff = ks * 32 + quad * 8;
                A[pt2][ks][0] = *(const bf16x8*)(nrow + 0 * PLN + aoff);
                A[pt2][ks][1] = *(const bf16x8*)(nrow + 1 * PLN + aoff);
                A[pt2][ks][2] = *(const bf16x8*)(nrow + 2 * PLN + aoff);
            }
        }

        f32x4 acc[2][4];
#pragma unroll
        for (int pt2 = 0; pt2 < 2; ++pt2)
#pragma unroll
            for (int nt = 0; nt < 4; ++nt)
                acc[pt2][nt] = (f32x4){0.f, 0.f, 0.f, 0.f};

#pragma unroll
        for (int ks = 0; ks < 2; ++ks)
#pragma unroll
            for (int nt = 0; nt < 4; ++nt) {
                int boff = (nt * 16 + col) * 72 + ks * 32 + quad * 8;
                bf16x8 BH = *(bf16x8*)&wLDS[0][boff];
                bf16x8 BM = *(bf16x8*)&wLDS[1][boff];
                bf16x8 BL = *(bf16x8*)&wLDS[2][boff];
#pragma unroll
                for (int pt2 = 0; pt2 < 2; ++pt2) {
                    f32x4 a = acc[pt2][nt];
                    MFMA6(a, A[pt2][ks][0], A[pt2][ks][1], A[pt2][ks][2], BH, BM, BL)
                    acc[pt2][nt] = a;
                }
            }

#pragma unroll
        for (int pt2 = 0; pt2 < 2; ++pt2) {
            int pl = wv * 4 + pr * 2 + pt2;
            int pglob = p0 + pl;
            float res[4];
#pragma unroll
            for (int nt = 0; nt < 4; ++nt) {
                float base = baseS[pl * 68 + nt * 16 + col];
                f32x4 a = acc[pt2][nt];
                float v0 = fmaf(base + a[0], scv[nt], bov[nt]);
                float v1 = fmaf(base + a[1], scv[nt], bov[nt]);
                float v2 = fmaf(base + a[2], scv[nt], bov[nt]);
                float v3 = fmaf(base + a[3], scv[nt], bov[nt]);
                float vm = fmaxf(fmaxf(v0, v1), fmaxf(v2, v3));
                vm = fmaxf(vm, __shfl_xor(vm, 16));
                vm = fmaxf(vm, __shfl_xor(vm, 32));
                res[nt] = fmaxf(vm, 0.0f);
            }
            float rv = res[quad];
            short hs_, ms_, ls_;
            split3(rv, hs_, ms_, ls_);
            hSout[0 * PLN + (size_t)pglob * Hh + lane] = hs_;
            hSout[1 * PLN + (size_t)pglob * Hh + lane] = ms_;
            hSout[2 * PLN + (size_t)pglob * Hh + lane] = ls_;

            float s = res[0] * res[0] + res[1] * res[1]
                    + res[2] * res[2] + res[3] * res[3];
            s += __shfl_xor(s, 1);
            s += __shfl_xor(s, 2);
            s += __shfl_xor(s, 4);
            s += __shfl_xor(s, 8);
            if (lane == 0) sqout[pglob] = s;
        }
    }
}

// ---------------------------------------------------------------------------
// head via MFMA (unchanged)
// ---------------------------------------------------------------------------
__global__ __launch_bounds__(256) void k_head(
    const short* __restrict__ hS, const short* __restrict__ wSs1,
    const float* __restrict__ g1, const float* __restrict__ b1,
    const float* __restrict__ w2, const float* __restrict__ b2,
    float* __restrict__ out)
{
    __shared__ short wLDS[3][64 * 80];
    __shared__ float partS[16][4];

    int t  = threadIdx.x;
    int p0 = blockIdx.x * 16;

#pragma unroll
    for (int it = 0; it < 6; ++it) {
        int f = it * 256 + t;
        int plane = f >> 9, i8 = f & 511;
        int o = i8 >> 3, c8 = i8 & 7;
        uint4 v = ((const uint4*)(wSs1 + (size_t)plane * 4096))[i8];
        *(uint4*)&wLDS[plane][o * 80 + c8 * 8] = v;
    }
    __syncthreads();

    int wv = t >> 6, lane = t & 63, col = lane & 15, quad = lane >> 4;

    const short* crow = hS + (size_t)(p0 + col) * Hh;
    f32x4 acc = (f32x4){0.f, 0.f, 0.f, 0.f};
#pragma unroll
    for (int ks = 0; ks < 2; ++ks) {
        int aoff = ks * 32 + quad * 8;
        bf16x8 AH = *(const bf16x8*)(crow + 0 * PLN + aoff);
        bf16x8 AM = *(const bf16x8*)(crow + 1 * PLN + aoff);
        bf16x8 AL = *(const bf16x8*)(crow + 2 * PLN + aoff);
        int boff = (wv * 16 + col) * 80 + aoff;
        bf16x8 BH = *(bf16x8*)&wLDS[0][boff];
        bf16x8 BM = *(bf16x8*)&wLDS[1][boff];
        bf16x8 BL = *(bf16x8*)&wLDS[2][boff];
        MFMA6(acc, AH, AM, AL, BH, BM, BL)
    }

    int o = wv * 16 + col;
    const float inv = rsqrtf(1.0f + EPSf);
    float sc = g1[o] * inv, bo = b1[o], w2o = w2[o];
    float s4[4];
#pragma unroll
    for (int r = 0; r < 4; ++r) {
        float a = fmaxf(fmaf(acc[r], sc, bo), 0.0f);
        s4[r] = a * w2o;
    }
#pragma unroll
    for (int sh = 1; sh < 16; sh <<= 1) {
#pragma unroll
        for (int r = 0; r < 4; ++r) s4[r] += __shfl_xor(s4[r], sh, 64);
    }
    if (col == 0) {
#pragma unroll
        for (int r = 0; r < 4; ++r) partS[quad * 4 + r][wv] = s4[r];
    }
    __syncthreads();
    if (t < 16)
        out[p0 + t] = partS[t][0] + partS[t][1] + partS[t][2] + partS[t][3] + b2[0];
}

// ---------------------------------------------------------------------------
extern "C" void kernel_launch(void* const* d_in, const int* in_sizes, int n_in,
                              void* d_out, int out_size, void* d_ws, size_t ws_size,
                              hipStream_t stream)
{
    const float* x    = (const float*)d_in[0];
    const float* w_t1 = (const float*)d_in[1];
    const float* g_t1 = (const float*)d_in[2];
    const float* b_t1 = (const float*)d_in[3];
    const float* w_t2 = (const float*)d_in[4];
    const float* g_t2 = (const float*)d_in[5];
    const float* b_t2 = (const float*)d_in[6];
    const float* w_nb = (const float*)d_in[7];
    const float* g_nb = (const float*)d_in[8];
    const float* b_nb = (const float*)d_in[9];
    const float* w_s1 = (const float*)d_in[10];
    const float* g_s1 = (const float*)d_in[11];
    const float* b_s1 = (const float*)d_in[12];
    const float* w_s2 = (const float*)d_in[13];
    const float* b_s2 = (const float*)d_in[14];
    float* out = (float*)d_out;

    float* sq  = (float*)d_ws;
    int*   idx = (int*)(sq + (size_t)Bn * Nn);
    short* hSa = (short*)(idx + (size_t)Bn * Nn * Kk);
    short* hSb = hSa + 3 * PLN;
    short* wS  = hSb + 3 * PLN;            // 18 planes x 4096 shorts
    unsigned int* keysG = (unsigned int*)(wS + (size_t)18 * 4096);  // 134 MB

    k_prep<<<64, 256, 0, stream>>>(w_nb, w_t2, w_s1, wS);
    k_t12<<<Bn * Nn / 16, 256, 0, stream>>>(x, w_t1, g_t1, b_t1,
                                            wS + (size_t)12 * 4096, g_t2, b_t2,
                                            hSa, sq);

    const short* hSin = hSa;
    short* hSout = hSb;
    for (int r = 0; r < Rr; ++r) {
        k_gram<<<Bn * (Nn / 16), 256, 0, stream>>>(hSin, sq, keysG);
        k_sel<<<Bn * (Nn / 4), 256, 0, stream>>>(keysG, idx);
        k_edge<<<Bn * Nn / 16, 256, 0, stream>>>(hSin, idx,
            wS + (size_t)r * 6 * 4096, g_nb + r * Hh, b_nb + r * Hh,
            hSout, sq);
        const short* ts = hSout; hSout = (short*)hSin; hSin = ts;
    }
    k_head<<<Bn * Nn / 16, 256, 0, stream>>>(hSin, wS + (size_t)15 * 4096,
                                             g_s1, b_s1, w_s2, b_s2, out);
}

// Round 17
// 473.059 us; speedup vs baseline: 1.3768x; 1.1524x over previous
//
#include <hip/hip_runtime.h>
#include <math.h>

#define Bn 128
#define Nn 512
#define Cc 7
#define Hh 64
#define Kk 16
#define Rr 2
#define EPSf 1e-5f

typedef __attribute__((ext_vector_type(8))) short bf16x8;
typedef __attribute__((ext_vector_type(4))) float f32x4;

#define PLN ((size_t)4194304)   // elements per h-split plane (B*N*H)

// exact truncation split: a = hi + mid + lo + r, |r| <= 2^-24 |a|
__device__ __forceinline__ void split3(float a, short &hs, short &ms, short &ls) {
    unsigned u  = __float_as_uint(a);
    unsigned hu = u & 0xFFFF0000u;
    float r1 = a - __uint_as_float(hu);
    unsigned mu = __float_as_uint(r1) & 0xFFFF0000u;
    float r2 = r1 - __uint_as_float(mu);
    unsigned lu = __float_as_uint(r2) & 0xFFFF0000u;
    hs = (short)(hu >> 16); ms = (short)(mu >> 16); ls = (short)(lu >> 16);
}

#define MFMA6(acc, AH, AM, AL, BH, BM, BL) \
    acc = __builtin_amdgcn_mfma_f32_16x16x32_bf16(AL, BH, acc, 0, 0, 0); \
    acc = __builtin_amdgcn_mfma_f32_16x16x32_bf16(AM, BM, acc, 0, 0, 0); \
    acc = __builtin_amdgcn_mfma_f32_16x16x32_bf16(AH, BL, acc, 0, 0, 0); \
    acc = __builtin_amdgcn_mfma_f32_16x16x32_bf16(AM, BH, acc, 0, 0, 0); \
    acc = __builtin_amdgcn_mfma_f32_16x16x32_bf16(AH, BM, acc, 0, 0, 0); \
    acc = __builtin_amdgcn_mfma_f32_16x16x32_bf16(AH, BH, acc, 0, 0, 0);

// ---------------------------------------------------------------------------
// prep: split weights into bf16x3 planes.
// wS layout (4096-short planes): [r0: wd x3, wcd x3][r1: wd x3, wcd x3]
//                                [w_t2 x3][w_s1 x3]   (18 planes total)
// ---------------------------------------------------------------------------
__global__ void k_prep(const float* __restrict__ w_nb, const float* __restrict__ w_t2,
                       const float* __restrict__ w_s1, short* __restrict__ wS)
{
    int i = blockIdx.x * 256 + threadIdx.x;     // 0 .. 16383
    short h_, m_, l_;
    if (i < 8192) {
        int r = i >> 12, oc = i & 4095;
        int o = oc >> 6, c = oc & 63;
        const float* wr = w_nb + (size_t)r * Hh * 2 * Hh + (size_t)o * 2 * Hh;
        float wc = wr[c], wd = wr[Hh + c];
        short* base = wS + (size_t)r * 6 * 4096;
        split3(wd, h_, m_, l_);
        base[0 * 4096 + oc] = h_; base[1 * 4096 + oc] = m_; base[2 * 4096 + oc] = l_;
        split3(wc - wd, h_, m_, l_);
        base[3 * 4096 + oc] = h_; base[4 * 4096 + oc] = m_; base[5 * 4096 + oc] = l_;
    } else {
        int which = (i - 8192) >> 12;            // 0: w_t2, 1: w_s1
        int oc = i & 4095;
        const float* src = which ? w_s1 : w_t2;
        short* base = wS + (size_t)(12 + which * 3) * 4096;
        split3(src[oc], h_, m_, l_);
        base[0 * 4096 + oc] = h_; base[1 * 4096 + oc] = m_; base[2 * 4096 + oc] = l_;
    }
}

// ---------------------------------------------------------------------------
// t1 + t2: layer 1 fp32 VALU (bit-exact), layer 2 via MFMA6 from split planes.
// ---------------------------------------------------------------------------
__global__ __launch_bounds__(256) void k_t12(
    const float* __restrict__ x,
    const float* __restrict__ w1, const float* __restrict__ g1, const float* __restrict__ b1,
    const short* __restrict__ wS2, const float* __restrict__ g2, const float* __restrict__ b2,
    short* __restrict__ hS, float* __restrict__ sq)
{
    __shared__ short wLDS[3][64 * 80];
    __shared__ short h1S[3][16 * 80];
    __shared__ float sqP[16][4];

    int t  = threadIdx.x;
    int p0 = blockIdx.x * 16;
    int b  = p0 >> 9, n0 = p0 & 511;

#pragma unroll
    for (int it = 0; it < 6; ++it) {
        int f = it * 256 + t;
        int plane = f >> 9, i8 = f & 511;
        int o = i8 >> 3, c8 = i8 & 7;
        uint4 v = ((const uint4*)(wS2 + (size_t)plane * 4096))[i8];
        *(uint4*)&wLDS[plane][o * 80 + c8 * 8] = v;
    }

    {
        int pt = t & 15, ow = t >> 4;
        const float inv = rsqrtf(1.0f + EPSf);
        float xv[Cc];
#pragma unroll
        for (int c = 0; c < Cc; ++c)
            xv[c] = x[(b * Cc + c) * Nn + n0 + pt];
#pragma unroll
        for (int j = 0; j < 4; ++j) {
            int o = ow + 16 * j;
            float acc = 0.0f;
#pragma unroll
            for (int c = 0; c < Cc; ++c)
                acc = fmaf(w1[o * Cc + c], xv[c], acc);
            acc = fmaf(acc, g1[o] * inv, b1[o]);
            acc = fmaxf(acc, 0.0f);
            short hs_, ms_, ls_;
            split3(acc, hs_, ms_, ls_);
            h1S[0][pt * 80 + o] = hs_;
            h1S[1][pt * 80 + o] = ms_;
            h1S[2][pt * 80 + o] = ls_;
        }
    }
    __syncthreads();

    int wv = t >> 6, lane = t & 63, col = lane & 15, quad = lane >> 4;
    const float inv = rsqrtf(1.0f + EPSf);

    f32x4 acc = (f32x4){0.f, 0.f, 0.f, 0.f};
#pragma unroll
    for (int ks = 0; ks < 2; ++ks) {
        int aoff = ks * 32 + quad * 8;
        bf16x8 AH = *(bf16x8*)&h1S[0][col * 80 + aoff];
        bf16x8 AM = *(bf16x8*)&h1S[1][col * 80 + aoff];
        bf16x8 AL = *(bf16x8*)&h1S[2][col * 80 + aoff];
        int boff = (wv * 16 + col) * 80 + aoff;
        bf16x8 BH = *(bf16x8*)&wLDS[0][boff];
        bf16x8 BM = *(bf16x8*)&wLDS[1][boff];
        bf16x8 BL = *(bf16x8*)&wLDS[2][boff];
        MFMA6(acc, AH, AM, AL, BH, BM, BL)
    }

    int o = wv * 16 + col;
    float sc = g2[o] * inv, bo = b2[o];
    float s4[4];
#pragma unroll
    for (int r = 0; r < 4; ++r) {
        int pt = quad * 4 + r;
        float a2 = fmaf(acc[r], sc, bo);
        a2 = fmaxf(a2, 0.0f);
        short hs_, ms_, ls_;
        split3(a2, hs_, ms_, ls_);
        size_t rowp = (size_t)(p0 + pt) * Hh + o;
        hS[0 * PLN + rowp] = hs_;
        hS[1 * PLN + rowp] = ms_;
        hS[2 * PLN + rowp] = ls_;
        s4[r] = a2 * a2;
    }
#pragma unroll
    for (int sh = 1; sh < 16; sh <<= 1) {
#pragma unroll
        for (int r = 0; r < 4; ++r) s4[r] += __shfl_xor(s4[r], sh, 64);
    }
    if (col == 0) {
#pragma unroll
        for (int r = 0; r < 4; ++r) sqP[quad * 4 + r][wv] = s4[r];
    }
    __syncthreads();
    if (t < 16) sq[p0 + t] = sqP[t][0] + sqP[t][1] + sqP[t][2] + sqP[t][3];
}

// ---------------------------------------------------------------------------
// kNN (R13 configuration — empirical best across R11-R16 probes):
// fused Gram-via-MFMA + keysLDS (34.8 KB, 4 blocks/CU, 64 VGPR no-spill) +
// 2-pass x 2-chain selection with pure-DPP min-reduce.
// ---------------------------------------------------------------------------
__global__ __launch_bounds__(256, 4) void k_knn(
    const short* __restrict__ hS, const float* __restrict__ sq, int* __restrict__ idxout)
{
    int xcd = blockIdx.x & 7;
    int s_  = blockIdx.x >> 3;
    int b   = xcd + ((s_ >> 5) << 3);
    int n0  = (s_ & 31) << 4;
    int t   = threadIdx.x;

    __shared__ unsigned int keysLDS[16 * 512];
    __shared__ float sqS[512];

    if (t < 128) ((float4*)sqS)[t] = ((const float4*)(sq + (size_t)b * Nn))[t];
    __syncthreads();

    int wv = t >> 6, lane = t & 63, col = lane & 15, quad = lane >> 4;
    const size_t rowbase = (size_t)b * Nn * Hh;

    bf16x8 AH[2], AM[2], AL[2];
    {
        const short* crow = hS + rowbase + (size_t)(n0 + col) * Hh;
#pragma unroll
        for (int ks = 0; ks < 2; ++ks) {
            int aoff = ks * 32 + quad * 8;
            AH[ks] = *(const bf16x8*)(crow + 0 * PLN + aoff);
            AM[ks] = *(const bf16x8*)(crow + 1 * PLN + aoff);
            AL[ks] = *(const bf16x8*)(crow + 2 * PLN + aoff);
        }
    }
    float sqcr[4];
#pragma unroll
    for (int r_ = 0; r_ < 4; ++r_) sqcr[r_] = sqS[n0 + quad * 4 + r_];

    for (int i = 0; i < 8; ++i) {
        int nt = wv * 8 + i;
        const short* prow = hS + rowbase + (size_t)(nt * 16 + col) * Hh;
        f32x4 acc = (f32x4){0.f, 0.f, 0.f, 0.f};
#pragma unroll
        for (int ks = 0; ks < 2; ++ks) {
            int aoff = ks * 32 + quad * 8;
            bf16x8 BH = *(const bf16x8*)(prow + 0 * PLN + aoff);
            bf16x8 BM = *(const bf16x8*)(prow + 1 * PLN + aoff);
            bf16x8 BL = *(const bf16x8*)(prow + 2 * PLN + aoff);
            MFMA6(acc, AH[ks], AM[ks], AL[ks], BH, BM, BL)
        }
        float sqp = sqS[nt * 16 + col];
#pragma unroll
        for (int r_ = 0; r_ < 4; ++r_) {
            int ctr = quad * 4 + r_;
            float d = sqcr[r_] + sqp - 2.0f * acc[r_];
            unsigned int u = __float_as_uint(d);
            u = ((int)u < 0) ? ~u : (u | 0x80000000u);
            keysLDS[ctr * 512 + nt * 16 + col] = u;
        }
    }
    __syncthreads();

    for (int pass = 0; pass < 2; ++pass) {
        unsigned int kk[2][8];
        int rr[2][8];
#pragma unroll
        for (int s = 0; s < 2; ++s) {
            int jj = wv * 4 + pass * 2 + s;
            const uint4* kp = (const uint4*)&keysLDS[jj * 512 + (lane << 3)];
            uint4 A = kp[0], Bq = kp[1];
            kk[s][0] = A.x;  kk[s][1] = A.y;  kk[s][2] = A.z;  kk[s][3] = A.w;
            kk[s][4] = Bq.x; kk[s][5] = Bq.y; kk[s][6] = Bq.z; kk[s][7] = Bq.w;
#pragma unroll
            for (int q = 0; q < 8; ++q) rr[s][q] = q;
        }

#define CE(s, i, j_) { \
    bool sw = (kk[s][i] > kk[s][j_]) || (kk[s][i] == kk[s][j_] && rr[s][i] > rr[s][j_]); \
    unsigned int tk = sw ? kk[s][i] : kk[s][j_]; kk[s][i] = sw ? kk[s][j_] : kk[s][i]; kk[s][j_] = tk; \
    int tr = sw ? rr[s][i] : rr[s][j_]; rr[s][i] = sw ? rr[s][j_] : rr[s][i]; rr[s][j_] = tr; }
#pragma unroll
        for (int s = 0; s < 2; ++s) {
            CE(s,0,1) CE(s,2,3) CE(s,4,5) CE(s,6,7)
            CE(s,0,2) CE(s,1,3) CE(s,4,6) CE(s,5,7)
            CE(s,1,2) CE(s,5,6)
            CE(s,0,4) CE(s,1,5) CE(s,2,6) CE(s,3,7)
            CE(s,2,4) CE(s,3,5)
            CE(s,1,2) CE(s,3,4) CE(s,5,6)
        }
#undef CE

        int outbase[2];
#pragma unroll
        for (int s = 0; s < 2; ++s)
            outbase[s] = (b * Nn + n0 + wv * 4 + pass * 2 + s) * Kk;

        for (int iter = 0; iter < Kk; ++iter) {
            unsigned int mv[2];
#pragma unroll
            for (int s = 0; s < 2; ++s) mv[s] = kk[s][0];
#define DSTEP(ctrl) { \
        _Pragma("unroll") \
        for (int s = 0; s < 2; ++s) { \
            unsigned int ov = (unsigned int)__builtin_amdgcn_update_dpp((int)mv[s], (int)mv[s], ctrl, 0xF, 0xF, false); \
            mv[s] = (ov < mv[s]) ? ov : mv[s]; } }
            DSTEP(0xB1)    // quad_perm xor1
            DSTEP(0x4E)    // quad_perm xor2
            DSTEP(0x124)   // row_ror:4
            DSTEP(0x128)   // row_ror:8     -> each row16 uniform
            DSTEP(0x142)   // row_bcast15
            DSTEP(0x143)   // row_bcast31   -> lane63 holds full min
#undef DSTEP
            unsigned int m[2];
#pragma unroll
            for (int s = 0; s < 2; ++s)
                m[s] = (unsigned int)__builtin_amdgcn_readlane((int)mv[s], 63);
#pragma unroll
            for (int s = 0; s < 2; ++s) {
                unsigned long long bal = __ballot(kk[s][0] == m[s]);
                int wn = __ffsll(bal) - 1;
                if (lane == wn) {
                    idxout[outbase[s] + iter] = (lane << 3) + rr[s][0];
#pragma unroll
                    for (int q = 0; q < 7; ++q) { kk[s][q] = kk[s][q + 1]; rr[s][q] = rr[s][q + 1]; }
                    kk[s][7] = 0xFFFFFFFFu;
                }
            }
        }
    }
}

// ---------------------------------------------------------------------------
// EdgeConv via MFMA, base/delta, XCD swizzle
// ---------------------------------------------------------------------------
__global__ __launch_bounds__(256, 4) void k_edge(
    const short* __restrict__ hS,
    const int* __restrict__ idx,
    const short* __restrict__ wS,
    const float* __restrict__ g, const float* __restrict__ bb_,
    short* __restrict__ hSout, float* __restrict__ sqout)
{
    __shared__ short wLDS[3][64 * 72];
    __shared__ float baseS[16 * 68];
    __shared__ int   idxS[256];

    int t   = threadIdx.x;
    int xcd = blockIdx.x & 7;
    int s_  = blockIdx.x >> 3;
    int b   = xcd + ((s_ >> 5) << 3);
    int p0  = b * Nn + ((s_ & 31) << 4);

    idxS[t] = idx[p0 * Kk + t];
#pragma unroll
    for (int it = 0; it < 6; ++it) {
        int f = it * 256 + t;
        int plane = f >> 9;
        int i8 = f & 511;
        int o = i8 >> 3, c8 = i8 & 7;
        uint4 v = ((const uint4*)(wS + (size_t)(3 + plane) * 4096))[i8];
        *(uint4*)&wLDS[plane][o * 72 + c8 * 8] = v;
    }
    __syncthreads();

    int wv = t >> 6, lane = t & 63, col = lane & 15, quad = lane >> 4;

    {
        f32x4 bacc = (f32x4){0.f, 0.f, 0.f, 0.f};
        const short* hrow = hS + (size_t)(p0 + col) * Hh;
#pragma unroll
        for (int ks = 0; ks < 2; ++ks) {
            int aoff = ks * 32 + quad * 8;
            bf16x8 AH = *(const bf16x8*)(hrow + 0 * PLN + aoff);
            bf16x8 AM = *(const bf16x8*)(hrow + 1 * PLN + aoff);
            bf16x8 AL = *(const bf16x8*)(hrow + 2 * PLN + aoff);
            int boff = (wv * 16 + col) * 72 + aoff;
            bf16x8 BH = *(bf16x8*)&wLDS[0][boff];
            bf16x8 BM = *(bf16x8*)&wLDS[1][boff];
            bf16x8 BL = *(bf16x8*)&wLDS[2][boff];
            MFMA6(bacc, AH, AM, AL, BH, BM, BL)
        }
#pragma unroll
        for (int r_ = 0; r_ < 4; ++r_)
            baseS[(quad * 4 + r_) * 68 + wv * 16 + col] = bacc[r_];
    }
    __syncthreads();

#pragma unroll
    for (int it = 0; it < 6; ++it) {
        int f = it * 256 + t;
        int plane = f >> 9;
        int i8 = f & 511;
        int o = i8 >> 3, c8 = i8 & 7;
        uint4 v = ((const uint4*)(wS + (size_t)plane * 4096))[i8];
        *(uint4*)&wLDS[plane][o * 72 + c8 * 8] = v;
    }
    __syncthreads();

    const float inv = rsqrtf(1.0f + EPSf);
    float scv[4], bov[4];
#pragma unroll
    for (int nt = 0; nt < 4; ++nt) {
        scv[nt] = g[nt * 16 + col] * inv;
        bov[nt] = bb_[nt * 16 + col];
    }

    for (int pr = 0; pr < 2; ++pr) {
        bf16x8 A[2][2][3];
#pragma unroll
        for (int pt2 = 0; pt2 < 2; ++pt2) {
            int pl = wv * 4 + pr * 2 + pt2;
            int j = idxS[pl * 16 + col];
            const short* nrow = hS + ((size_t)(b * Nn) + j) * Hh;
#pragma unroll
            for (int ks = 0; ks < 2; ++ks) {
                int aoff = ks * 32 + quad * 8;
                A[pt2][ks][0] = *(const bf16x8*)(nrow + 0 * PLN + aoff);
                A[pt2][ks][1] = *(const bf16x8*)(nrow + 1 * PLN + aoff);
                A[pt2][ks][2] = *(const bf16x8*)(nrow + 2 * PLN + aoff);
            }
        }

        f32x4 acc[2][4];
#pragma unroll
        for (int pt2 = 0; pt2 < 2; ++pt2)
#pragma unroll
            for (int nt = 0; nt < 4; ++nt)
                acc[pt2][nt] = (f32x4){0.f, 0.f, 0.f, 0.f};

#pragma unroll
        for (int ks = 0; ks < 2; ++ks)
#pragma unroll
            for (int nt = 0; nt < 4; ++nt) {
                int boff = (nt * 16 + col) * 72 + ks * 32 + quad * 8;
                bf16x8 BH = *(bf16x8*)&wLDS[0][boff];
                bf16x8 BM = *(bf16x8*)&wLDS[1][boff];
                bf16x8 BL = *(bf16x8*)&wLDS[2][boff];
#pragma unroll
                for (int pt2 = 0; pt2 < 2; ++pt2) {
                    f32x4 a = acc[pt2][nt];
                    MFMA6(a, A[pt2][ks][0], A[pt2][ks][1], A[pt2][ks][2], BH, BM, BL)
                    acc[pt2][nt] = a;
                }
            }

#pragma unroll
        for (int pt2 = 0; pt2 < 2; ++pt2) {
            int pl = wv * 4 + pr * 2 + pt2;
            int pglob = p0 + pl;
            float res[4];
#pragma unroll
            for (int nt = 0; nt < 4; ++nt) {
                float base = baseS[pl * 68 + nt * 16 + col];
                f32x4 a = acc[pt2][nt];
                float v0 = fmaf(base + a[0], scv[nt], bov[nt]);
                float v1 = fmaf(base + a[1], scv[nt], bov[nt]);
                float v2 = fmaf(base + a[2], scv[nt], bov[nt]);
                float v3 = fmaf(base + a[3], scv[nt], bov[nt]);
                float vm = fmaxf(fmaxf(v0, v1), fmaxf(v2, v3));
                vm = fmaxf(vm, __shfl_xor(vm, 16));
                vm = fmaxf(vm, __shfl_xor(vm, 32));
                res[nt] = fmaxf(vm, 0.0f);
            }
            float rv = res[quad];
            short hs_, ms_, ls_;
            split3(rv, hs_, ms_, ls_);
            hSout[0 * PLN + (size_t)pglob * Hh + lane] = hs_;
            hSout[1 * PLN + (size_t)pglob * Hh + lane] = ms_;
            hSout[2 * PLN + (size_t)pglob * Hh + lane] = ls_;

            float s = res[0] * res[0] + res[1] * res[1]
                    + res[2] * res[2] + res[3] * res[3];
            s += __shfl_xor(s, 1);
            s += __shfl_xor(s, 2);
            s += __shfl_xor(s, 4);
            s += __shfl_xor(s, 8);
            if (lane == 0) sqout[pglob] = s;
        }
    }
}

// ---------------------------------------------------------------------------
// head via MFMA
// ---------------------------------------------------------------------------
__global__ __launch_bounds__(256) void k_head(
    const short* __restrict__ hS, const short* __restrict__ wSs1,
    const float* __restrict__ g1, const float* __restrict__ b1,
    const float* __restrict__ w2, const float* __restrict__ b2,
    float* __restrict__ out)
{
    __shared__ short wLDS[3][64 * 80];
    __shared__ float partS[16][4];

    int t  = threadIdx.x;
    int p0 = blockIdx.x * 16;

#pragma unroll
    for (int it = 0; it < 6; ++it) {
        int f = it * 256 + t;
        int plane = f >> 9, i8 = f & 511;
        int o = i8 >> 3, c8 = i8 & 7;
        uint4 v = ((const uint4*)(wSs1 + (size_t)plane * 4096))[i8];
        *(uint4*)&wLDS[plane][o * 80 + c8 * 8] = v;
    }
    __syncthreads();

    int wv = t >> 6, lane = t & 63, col = lane & 15, quad = lane >> 4;

    const short* crow = hS + (size_t)(p0 + col) * Hh;
    f32x4 acc = (f32x4){0.f, 0.f, 0.f, 0.f};
#pragma unroll
    for (int ks = 0; ks < 2; ++ks) {
        int aoff = ks * 32 + quad * 8;
        bf16x8 AH = *(const bf16x8*)(crow + 0 * PLN + aoff);
        bf16x8 AM = *(const bf16x8*)(crow + 1 * PLN + aoff);
        bf16x8 AL = *(const bf16x8*)(crow + 2 * PLN + aoff);
        int boff = (wv * 16 + col) * 80 + aoff;
        bf16x8 BH = *(bf16x8*)&wLDS[0][boff];
        bf16x8 BM = *(bf16x8*)&wLDS[1][boff];
        bf16x8 BL = *(bf16x8*)&wLDS[2][boff];
        MFMA6(acc, AH, AM, AL, BH, BM, BL)
    }

    int o = wv * 16 + col;
    const float inv = rsqrtf(1.0f + EPSf);
    float sc = g1[o] * inv, bo = b1[o], w2o = w2[o];
    float s4[4];
#pragma unroll
    for (int r = 0; r < 4; ++r) {
        float a = fmaxf(fmaf(acc[r], sc, bo), 0.0f);
        s4[r] = a * w2o;
    }
#pragma unroll
    for (int sh = 1; sh < 16; sh <<= 1) {
#pragma unroll
        for (int r = 0; r < 4; ++r) s4[r] += __shfl_xor(s4[r], sh, 64);
    }
    if (col == 0) {
#pragma unroll
        for (int r = 0; r < 4; ++r) partS[quad * 4 + r][wv] = s4[r];
    }
    __syncthreads();
    if (t < 16)
        out[p0 + t] = partS[t][0] + partS[t][1] + partS[t][2] + partS[t][3] + b2[0];
}

// ---------------------------------------------------------------------------
extern "C" void kernel_launch(void* const* d_in, const int* in_sizes, int n_in,
                              void* d_out, int out_size, void* d_ws, size_t ws_size,
                              hipStream_t stream)
{
    const float* x    = (const float*)d_in[0];
    const float* w_t1 = (const float*)d_in[1];
    const float* g_t1 = (const float*)d_in[2];
    const float* b_t1 = (const float*)d_in[3];
    const float* w_t2 = (const float*)d_in[4];
    const float* g_t2 = (const float*)d_in[5];
    const float* b_t2 = (const float*)d_in[6];
    const float* w_nb = (const float*)d_in[7];
    const float* g_nb = (const float*)d_in[8];
    const float* b_nb = (const float*)d_in[9];
    const float* w_s1 = (const float*)d_in[10];
    const float* g_s1 = (const float*)d_in[11];
    const float* b_s1 = (const float*)d_in[12];
    const float* w_s2 = (const float*)d_in[13];
    const float* b_s2 = (const float*)d_in[14];
    float* out = (float*)d_out;

    float* sq  = (float*)d_ws;
    int*   idx = (int*)(sq + (size_t)Bn * Nn);
    short* hSa = (short*)(idx + (size_t)Bn * Nn * Kk);
    short* hSb = hSa + 3 * PLN;
    short* wS  = hSb + 3 * PLN;            // 18 planes x 4096 shorts

    k_prep<<<64, 256, 0, stream>>>(w_nb, w_t2, w_s1, wS);
    k_t12<<<Bn * Nn / 16, 256, 0, stream>>>(x, w_t1, g_t1, b_t1,
                                            wS + (size_t)12 * 4096, g_t2, b_t2,
                                            hSa, sq);

    const short* hSin = hSa;
    short* hSout = hSb;
    for (int r = 0; r < Rr; ++r) {
        k_knn<<<Bn * (Nn / 16), 256, 0, stream>>>(hSin, sq, idx);
        k_edge<<<Bn * Nn / 16, 256, 0, stream>>>(hSin, idx,
            wS + (size_t)r * 6 * 4096, g_nb + r * Hh, b_nb + r * Hh,
            hSout, sq);
        const short* ts = hSout; hSout = (short*)hSin; hSin = ts;
    }
    k_head<<<Bn * Nn / 16, 256, 0, stream>>>(hSin, wS + (size_t)15 * 4096,
                                             g_s1, b_s1, w_s2, b_s2, out);
}

// Round 18
// 466.201 us; speedup vs baseline: 1.3971x; 1.0147x over previous
//
#include <hip/hip_runtime.h>
#include <math.h>

#define Bn 128
#define Nn 512
#define Cc 7
#define Hh 64
#define Kk 16
#define Rr 2
#define EPSf 1e-5f

typedef __attribute__((ext_vector_type(8))) short bf16x8;
typedef __attribute__((ext_vector_type(4))) float f32x4;

#define PLN ((size_t)4194304)   // elements per h-split plane (B*N*H)

// exact truncation split: a = hi + mid + lo + r, |r| <= 2^-24 |a|
__device__ __forceinline__ void split3(float a, short &hs, short &ms, short &ls) {
    unsigned u  = __float_as_uint(a);
    unsigned hu = u & 0xFFFF0000u;
    float r1 = a - __uint_as_float(hu);
    unsigned mu = __float_as_uint(r1) & 0xFFFF0000u;
    float r2 = r1 - __uint_as_float(mu);
    unsigned lu = __float_as_uint(r2) & 0xFFFF0000u;
    hs = (short)(hu >> 16); ms = (short)(mu >> 16); ls = (short)(lu >> 16);
}

#define MFMA6(acc, AH, AM, AL, BH, BM, BL) \
    acc = __builtin_amdgcn_mfma_f32_16x16x32_bf16(AL, BH, acc, 0, 0, 0); \
    acc = __builtin_amdgcn_mfma_f32_16x16x32_bf16(AM, BM, acc, 0, 0, 0); \
    acc = __builtin_amdgcn_mfma_f32_16x16x32_bf16(AH, BL, acc, 0, 0, 0); \
    acc = __builtin_amdgcn_mfma_f32_16x16x32_bf16(AM, BH, acc, 0, 0, 0); \
    acc = __builtin_amdgcn_mfma_f32_16x16x32_bf16(AH, BM, acc, 0, 0, 0); \
    acc = __builtin_amdgcn_mfma_f32_16x16x32_bf16(AH, BH, acc, 0, 0, 0);

// ---------------------------------------------------------------------------
// prep: split weights into bf16x3 planes.
// wS layout (4096-short planes): [r0: wd x3, wcd x3][r1: wd x3, wcd x3]
//                                [w_t2 x3][w_s1 x3]   (18 planes total)
// ---------------------------------------------------------------------------
__global__ void k_prep(const float* __restrict__ w_nb, const float* __restrict__ w_t2,
                       const float* __restrict__ w_s1, short* __restrict__ wS)
{
    int i = blockIdx.x * 256 + threadIdx.x;     // 0 .. 16383
    short h_, m_, l_;
    if (i < 8192) {
        int r = i >> 12, oc = i & 4095;
        int o = oc >> 6, c = oc & 63;
        const float* wr = w_nb + (size_t)r * Hh * 2 * Hh + (size_t)o * 2 * Hh;
        float wc = wr[c], wd = wr[Hh + c];
        short* base = wS + (size_t)r * 6 * 4096;
        split3(wd, h_, m_, l_);
        base[0 * 4096 + oc] = h_; base[1 * 4096 + oc] = m_; base[2 * 4096 + oc] = l_;
        split3(wc - wd, h_, m_, l_);
        base[3 * 4096 + oc] = h_; base[4 * 4096 + oc] = m_; base[5 * 4096 + oc] = l_;
    } else {
        int which = (i - 8192) >> 12;            // 0: w_t2, 1: w_s1
        int oc = i & 4095;
        const float* src = which ? w_s1 : w_t2;
        short* base = wS + (size_t)(12 + which * 3) * 4096;
        split3(src[oc], h_, m_, l_);
        base[0 * 4096 + oc] = h_; base[1 * 4096 + oc] = m_; base[2 * 4096 + oc] = l_;
    }
}

// ---------------------------------------------------------------------------
// t1 + t2: layer 1 fp32 VALU (bit-exact), layer 2 via MFMA6 from split planes.
// ---------------------------------------------------------------------------
__global__ __launch_bounds__(256) void k_t12(
    const float* __restrict__ x,
    const float* __restrict__ w1, const float* __restrict__ g1, const float* __restrict__ b1,
    const short* __restrict__ wS2, const float* __restrict__ g2, const float* __restrict__ b2,
    short* __restrict__ hS, float* __restrict__ sq)
{
    __shared__ short wLDS[3][64 * 80];
    __shared__ short h1S[3][16 * 80];
    __shared__ float sqP[16][4];

    int t  = threadIdx.x;
    int p0 = blockIdx.x * 16;
    int b  = p0 >> 9, n0 = p0 & 511;

#pragma unroll
    for (int it = 0; it < 6; ++it) {
        int f = it * 256 + t;
        int plane = f >> 9, i8 = f & 511;
        int o = i8 >> 3, c8 = i8 & 7;
        uint4 v = ((const uint4*)(wS2 + (size_t)plane * 4096))[i8];
        *(uint4*)&wLDS[plane][o * 80 + c8 * 8] = v;
    }

    {
        int pt = t & 15, ow = t >> 4;
        const float inv = rsqrtf(1.0f + EPSf);
        float xv[Cc];
#pragma unroll
        for (int c = 0; c < Cc; ++c)
            xv[c] = x[(b * Cc + c) * Nn + n0 + pt];
#pragma unroll
        for (int j = 0; j < 4; ++j) {
            int o = ow + 16 * j;
            float acc = 0.0f;
#pragma unroll
            for (int c = 0; c < Cc; ++c)
                acc = fmaf(w1[o * Cc + c], xv[c], acc);
            acc = fmaf(acc, g1[o] * inv, b1[o]);
            acc = fmaxf(acc, 0.0f);
            short hs_, ms_, ls_;
            split3(acc, hs_, ms_, ls_);
            h1S[0][pt * 80 + o] = hs_;
            h1S[1][pt * 80 + o] = ms_;
            h1S[2][pt * 80 + o] = ls_;
        }
    }
    __syncthreads();

    int wv = t >> 6, lane = t & 63, col = lane & 15, quad = lane >> 4;
    const float inv = rsqrtf(1.0f + EPSf);

    f32x4 acc = (f32x4){0.f, 0.f, 0.f, 0.f};
#pragma unroll
    for (int ks = 0; ks < 2; ++ks) {
        int aoff = ks * 32 + quad * 8;
        bf16x8 AH = *(bf16x8*)&h1S[0][col * 80 + aoff];
        bf16x8 AM = *(bf16x8*)&h1S[1][col * 80 + aoff];
        bf16x8 AL = *(bf16x8*)&h1S[2][col * 80 + aoff];
        int boff = (wv * 16 + col) * 80 + aoff;
        bf16x8 BH = *(bf16x8*)&wLDS[0][boff];
        bf16x8 BM = *(bf16x8*)&wLDS[1][boff];
        bf16x8 BL = *(bf16x8*)&wLDS[2][boff];
        MFMA6(acc, AH, AM, AL, BH, BM, BL)
    }

    int o = wv * 16 + col;
    float sc = g2[o] * inv, bo = b2[o];
    float s4[4];
#pragma unroll
    for (int r = 0; r < 4; ++r) {
        int pt = quad * 4 + r;
        float a2 = fmaf(acc[r], sc, bo);
        a2 = fmaxf(a2, 0.0f);
        short hs_, ms_, ls_;
        split3(a2, hs_, ms_, ls_);
        size_t rowp = (size_t)(p0 + pt) * Hh + o;
        hS[0 * PLN + rowp] = hs_;
        hS[1 * PLN + rowp] = ms_;
        hS[2 * PLN + rowp] = ls_;
        s4[r] = a2 * a2;
    }
#pragma unroll
    for (int sh = 1; sh < 16; sh <<= 1) {
#pragma unroll
        for (int r = 0; r < 4; ++r) s4[r] += __shfl_xor(s4[r], sh, 64);
    }
    if (col == 0) {
#pragma unroll
        for (int r = 0; r < 4; ++r) sqP[quad * 4 + r][wv] = s4[r];
    }
    __syncthreads();
    if (t < 16) sq[p0 + t] = sqP[t][0] + sqP[t][1] + sqP[t][2] + sqP[t][3];
}

// ---------------------------------------------------------------------------
// FUSED kNN + EdgeConv. Block = 16 centers == the same 16 points.
// Phase 1: Gram via MFMA -> keys in LDS; 2-pass x 2-chain DPP selection ->
// idx in LDS (R13/R17 logic byte-for-byte -> bit-identical indices).
// Phase 2: base/delta EdgeConv via MFMA (R17 k_edge verbatim), W planes
// staged into the SAME LDS region (union; barrier-ordered). sq is
// double-buffered (sqin/sqout) because blocks of one dispatch mix phases.
// ---------------------------------------------------------------------------
union KnnEdgeLDS {
    unsigned int keys[16 * 512];               // 32 KB (phase 1)
    struct {
        short wLDS[3][64 * 72];                // 27.6 KB (phase 2)
        float baseS[16 * 68];                  // 4.35 KB
    } p2;
};

__global__ __launch_bounds__(256, 4) void k_knn_edge(
    const short* __restrict__ hS, const float* __restrict__ sqin,
    const short* __restrict__ wS,
    const float* __restrict__ g, const float* __restrict__ bb_,
    short* __restrict__ hSout, float* __restrict__ sqout)
{
    __shared__ KnnEdgeLDS u;
    __shared__ float sqS[512];
    __shared__ int   idxS[256];

    int t   = threadIdx.x;
    int xcd = blockIdx.x & 7;
    int s_  = blockIdx.x >> 3;
    int b   = xcd + ((s_ >> 5) << 3);
    int n0  = (s_ & 31) << 4;
    int p0  = b * Nn + n0;

    if (t < 128) ((float4*)sqS)[t] = ((const float4*)(sqin + (size_t)b * Nn))[t];
    __syncthreads();

    int wv = t >> 6, lane = t & 63, col = lane & 15, quad = lane >> 4;
    const size_t rowbase = (size_t)b * Nn * Hh;

    // ================= phase 1a: Gram via MFMA =================
    {
        bf16x8 AH[2], AM[2], AL[2];
        const short* crow = hS + rowbase + (size_t)(n0 + col) * Hh;
#pragma unroll
        for (int ks = 0; ks < 2; ++ks) {
            int aoff = ks * 32 + quad * 8;
            AH[ks] = *(const bf16x8*)(crow + 0 * PLN + aoff);
            AM[ks] = *(const bf16x8*)(crow + 1 * PLN + aoff);
            AL[ks] = *(const bf16x8*)(crow + 2 * PLN + aoff);
        }
        float sqcr[4];
#pragma unroll
        for (int r_ = 0; r_ < 4; ++r_) sqcr[r_] = sqS[n0 + quad * 4 + r_];

        for (int i = 0; i < 8; ++i) {
            int nt = wv * 8 + i;
            const short* prow = hS + rowbase + (size_t)(nt * 16 + col) * Hh;
            f32x4 acc = (f32x4){0.f, 0.f, 0.f, 0.f};
#pragma unroll
            for (int ks = 0; ks < 2; ++ks) {
                int aoff = ks * 32 + quad * 8;
                bf16x8 BH = *(const bf16x8*)(prow + 0 * PLN + aoff);
                bf16x8 BM = *(const bf16x8*)(prow + 1 * PLN + aoff);
                bf16x8 BL = *(const bf16x8*)(prow + 2 * PLN + aoff);
                MFMA6(acc, AH[ks], AM[ks], AL[ks], BH, BM, BL)
            }
            float sqp = sqS[nt * 16 + col];
#pragma unroll
            for (int r_ = 0; r_ < 4; ++r_) {
                int ctr = quad * 4 + r_;
                float d = sqcr[r_] + sqp - 2.0f * acc[r_];
                unsigned int uu = __float_as_uint(d);
                uu = ((int)uu < 0) ? ~uu : (uu | 0x80000000u);
                u.keys[ctr * 512 + nt * 16 + col] = uu;
            }
        }
    }
    __syncthreads();

    // ================= phase 1b: selection (2 passes x 2 chains) =========
    for (int pass = 0; pass < 2; ++pass) {
        unsigned int kk[2][8];
        int rr[2][8];
#pragma unroll
        for (int s = 0; s < 2; ++s) {
            int jj = wv * 4 + pass * 2 + s;
            const uint4* kp = (const uint4*)&u.keys[jj * 512 + (lane << 3)];
            uint4 A = kp[0], Bq = kp[1];
            kk[s][0] = A.x;  kk[s][1] = A.y;  kk[s][2] = A.z;  kk[s][3] = A.w;
            kk[s][4] = Bq.x; kk[s][5] = Bq.y; kk[s][6] = Bq.z; kk[s][7] = Bq.w;
#pragma unroll
            for (int q = 0; q < 8; ++q) rr[s][q] = q;
        }

#define CE(s, i, j_) { \
    bool sw = (kk[s][i] > kk[s][j_]) || (kk[s][i] == kk[s][j_] && rr[s][i] > rr[s][j_]); \
    unsigned int tk = sw ? kk[s][i] : kk[s][j_]; kk[s][i] = sw ? kk[s][j_] : kk[s][i]; kk[s][j_] = tk; \
    int tr = sw ? rr[s][i] : rr[s][j_]; rr[s][i] = sw ? rr[s][j_] : rr[s][i]; rr[s][j_] = tr; }
#pragma unroll
        for (int s = 0; s < 2; ++s) {
            CE(s,0,1) CE(s,2,3) CE(s,4,5) CE(s,6,7)
            CE(s,0,2) CE(s,1,3) CE(s,4,6) CE(s,5,7)
            CE(s,1,2) CE(s,5,6)
            CE(s,0,4) CE(s,1,5) CE(s,2,6) CE(s,3,7)
            CE(s,2,4) CE(s,3,5)
            CE(s,1,2) CE(s,3,4) CE(s,5,6)
        }
#undef CE

        int outbase[2];
#pragma unroll
        for (int s = 0; s < 2; ++s)
            outbase[s] = (wv * 4 + pass * 2 + s) * Kk;

        for (int iter = 0; iter < Kk; ++iter) {
            unsigned int mv[2];
#pragma unroll
            for (int s = 0; s < 2; ++s) mv[s] = kk[s][0];
#define DSTEP(ctrl) { \
        _Pragma("unroll") \
        for (int s = 0; s < 2; ++s) { \
            unsigned int ov = (unsigned int)__builtin_amdgcn_update_dpp((int)mv[s], (int)mv[s], ctrl, 0xF, 0xF, false); \
            mv[s] = (ov < mv[s]) ? ov : mv[s]; } }
            DSTEP(0xB1)    // quad_perm xor1
            DSTEP(0x4E)    // quad_perm xor2
            DSTEP(0x124)   // row_ror:4
            DSTEP(0x128)   // row_ror:8
            DSTEP(0x142)   // row_bcast15
            DSTEP(0x143)   // row_bcast31 -> lane63 holds full min
#undef DSTEP
            unsigned int m[2];
#pragma unroll
            for (int s = 0; s < 2; ++s)
                m[s] = (unsigned int)__builtin_amdgcn_readlane((int)mv[s], 63);
#pragma unroll
            for (int s = 0; s < 2; ++s) {
                unsigned long long bal = __ballot(kk[s][0] == m[s]);
                int wn = __ffsll(bal) - 1;
                if (lane == wn) {
                    idxS[outbase[s] + iter] = (lane << 3) + rr[s][0];
#pragma unroll
                    for (int q = 0; q < 7; ++q) { kk[s][q] = kk[s][q + 1]; rr[s][q] = rr[s][q + 1]; }
                    kk[s][7] = 0xFFFFFFFFu;
                }
            }
        }
    }
    __syncthreads();   // keys dead; idxS complete -> phase 2 may overwrite union

    // ================= phase 2: EdgeConv =================
    // stage wcd splits (planes 3..5)
#pragma unroll
    for (int it = 0; it < 6; ++it) {
        int f = it * 256 + t;
        int plane = f >> 9;
        int i8 = f & 511;
        int o = i8 >> 3, c8 = i8 & 7;
        uint4 v = ((const uint4*)(wS + (size_t)(3 + plane) * 4096))[i8];
        *(uint4*)&u.p2.wLDS[plane][o * 72 + c8 * 8] = v;
    }
    __syncthreads();

    {
        f32x4 bacc = (f32x4){0.f, 0.f, 0.f, 0.f};
        const short* hrow = hS + (size_t)(p0 + col) * Hh;
#pragma unroll
        for (int ks = 0; ks < 2; ++ks) {
            int aoff = ks * 32 + quad * 8;
            bf16x8 AH = *(const bf16x8*)(hrow + 0 * PLN + aoff);
            bf16x8 AM = *(const bf16x8*)(hrow + 1 * PLN + aoff);
            bf16x8 AL = *(const bf16x8*)(hrow + 2 * PLN + aoff);
            int boff = (wv * 16 + col) * 72 + aoff;
            bf16x8 BH = *(bf16x8*)&u.p2.wLDS[0][boff];
            bf16x8 BM = *(bf16x8*)&u.p2.wLDS[1][boff];
            bf16x8 BL = *(bf16x8*)&u.p2.wLDS[2][boff];
            MFMA6(bacc, AH, AM, AL, BH, BM, BL)
        }
#pragma unroll
        for (int r_ = 0; r_ < 4; ++r_)
            u.p2.baseS[(quad * 4 + r_) * 68 + wv * 16 + col] = bacc[r_];
    }
    __syncthreads();

    // overwrite with wd splits (planes 0..2)
#pragma unroll
    for (int it = 0; it < 6; ++it) {
        int f = it * 256 + t;
        int plane = f >> 9;
        int i8 = f & 511;
        int o = i8 >> 3, c8 = i8 & 7;
        uint4 v = ((const uint4*)(wS + (size_t)plane * 4096))[i8];
        *(uint4*)&u.p2.wLDS[plane][o * 72 + c8 * 8] = v;
    }
    __syncthreads();

    const float inv = rsqrtf(1.0f + EPSf);
    float scv[4], bov[4];
#pragma unroll
    for (int nt = 0; nt < 4; ++nt) {
        scv[nt] = g[nt * 16 + col] * inv;
        bov[nt] = bb_[nt * 16 + col];
    }

    for (int pr = 0; pr < 2; ++pr) {
        bf16x8 A[2][2][3];
#pragma unroll
        for (int pt2 = 0; pt2 < 2; ++pt2) {
            int pl = wv * 4 + pr * 2 + pt2;
            int j = idxS[pl * 16 + col];
            const short* nrow = hS + ((size_t)(b * Nn) + j) * Hh;
#pragma unroll
            for (int ks = 0; ks < 2; ++ks) {
                int aoff = ks * 32 + quad * 8;
                A[pt2][ks][0] = *(const bf16x8*)(nrow + 0 * PLN + aoff);
                A[pt2][ks][1] = *(const bf16x8*)(nrow + 1 * PLN + aoff);
                A[pt2][ks][2] = *(const bf16x8*)(nrow + 2 * PLN + aoff);
            }
        }

        f32x4 acc[2][4];
#pragma unroll
        for (int pt2 = 0; pt2 < 2; ++pt2)
#pragma unroll
            for (int nt = 0; nt < 4; ++nt)
                acc[pt2][nt] = (f32x4){0.f, 0.f, 0.f, 0.f};

#pragma unroll
        for (int ks = 0; ks < 2; ++ks)
#pragma unroll
            for (int nt = 0; nt < 4; ++nt) {
                int boff = (nt * 16 + col) * 72 + ks * 32 + quad * 8;
                bf16x8 BH = *(bf16x8*)&u.p2.wLDS[0][boff];
                bf16x8 BM = *(bf16x8*)&u.p2.wLDS[1][boff];
                bf16x8 BL = *(bf16x8*)&u.p2.wLDS[2][boff];
#pragma unroll
                for (int pt2 = 0; pt2 < 2; ++pt2) {
                    f32x4 a = acc[pt2][nt];
                    MFMA6(a, A[pt2][ks][0], A[pt2][ks][1], A[pt2][ks][2], BH, BM, BL)
                    acc[pt2][nt] = a;
                }
            }

#pragma unroll
        for (int pt2 = 0; pt2 < 2; ++pt2) {
            int pl = wv * 4 + pr * 2 + pt2;
            int pglob = p0 + pl;
            float res[4];
#pragma unroll
            for (int nt = 0; nt < 4; ++nt) {
                float base = u.p2.baseS[pl * 68 + nt * 16 + col];
                f32x4 a = acc[pt2][nt];
                float v0 = fmaf(base + a[0], scv[nt], bov[nt]);
                float v1 = fmaf(base + a[1], scv[nt], bov[nt]);
                float v2 = fmaf(base + a[2], scv[nt], bov[nt]);
                float v3 = fmaf(base + a[3], scv[nt], bov[nt]);
                float vm = fmaxf(fmaxf(v0, v1), fmaxf(v2, v3));
                vm = fmaxf(vm, __shfl_xor(vm, 16));
                vm = fmaxf(vm, __shfl_xor(vm, 32));
                res[nt] = fmaxf(vm, 0.0f);
            }
            float rv = res[quad];
            short hs_, ms_, ls_;
            split3(rv, hs_, ms_, ls_);
            hSout[0 * PLN + (size_t)pglob * Hh + lane] = hs_;
            hSout[1 * PLN + (size_t)pglob * Hh + lane] = ms_;
            hSout[2 * PLN + (size_t)pglob * Hh + lane] = ls_;

            float s = res[0] * res[0] + res[1] * res[1]
                    + res[2] * res[2] + res[3] * res[3];
            s += __shfl_xor(s, 1);
            s += __shfl_xor(s, 2);
            s += __shfl_xor(s, 4);
            s += __shfl_xor(s, 8);
            if (lane == 0) sqout[pglob] = s;
        }
    }
}

// ---------------------------------------------------------------------------
// head via MFMA
// ---------------------------------------------------------------------------
__global__ __launch_bounds__(256) void k_head(
    const short* __restrict__ hS, const short* __restrict__ wSs1,
    const float* __restrict__ g1, const float* __restrict__ b1,
    const float* __restrict__ w2, const float* __restrict__ b2,
    float* __restrict__ out)
{
    __shared__ short wLDS[3][64 * 80];
    __shared__ float partS[16][4];

    int t  = threadIdx.x;
    int p0 = blockIdx.x * 16;

#pragma unroll
    for (int it = 0; it < 6; ++it) {
        int f = it * 256 + t;
        int plane = f >> 9, i8 = f & 511;
        int o = i8 >> 3, c8 = i8 & 7;
        uint4 v = ((const uint4*)(wSs1 + (size_t)plane * 4096))[i8];
        *(uint4*)&wLDS[plane][o * 80 + c8 * 8] = v;
    }
    __syncthreads();

    int wv = t >> 6, lane = t & 63, col = lane & 15, quad = lane >> 4;

    const short* crow = hS + (size_t)(p0 + col) * Hh;
    f32x4 acc = (f32x4){0.f, 0.f, 0.f, 0.f};
#pragma unroll
    for (int ks = 0; ks < 2; ++ks) {
        int aoff = ks * 32 + quad * 8;
        bf16x8 AH = *(const bf16x8*)(crow + 0 * PLN + aoff);
        bf16x8 AM = *(const bf16x8*)(crow + 1 * PLN + aoff);
        bf16x8 AL = *(const bf16x8*)(crow + 2 * PLN + aoff);
        int boff = (wv * 16 + col) * 80 + aoff;
        bf16x8 BH = *(bf16x8*)&wLDS[0][boff];
        bf16x8 BM = *(bf16x8*)&wLDS[1][boff];
        bf16x8 BL = *(bf16x8*)&wLDS[2][boff];
        MFMA6(acc, AH, AM, AL, BH, BM, BL)
    }

    int o = wv * 16 + col;
    const float inv = rsqrtf(1.0f + EPSf);
    float sc = g1[o] * inv, bo = b1[o], w2o = w2[o];
    float s4[4];
#pragma unroll
    for (int r = 0; r < 4; ++r) {
        float a = fmaxf(fmaf(acc[r], sc, bo), 0.0f);
        s4[r] = a * w2o;
    }
#pragma unroll
    for (int sh = 1; sh < 16; sh <<= 1) {
#pragma unroll
        for (int r = 0; r < 4; ++r) s4[r] += __shfl_xor(s4[r], sh, 64);
    }
    if (col == 0) {
#pragma unroll
        for (int r = 0; r < 4; ++r) partS[quad * 4 + r][wv] = s4[r];
    }
    __syncthreads();
    if (t < 16)
        out[p0 + t] = partS[t][0] + partS[t][1] + partS[t][2] + partS[t][3] + b2[0];
}

// ---------------------------------------------------------------------------
extern "C" void kernel_launch(void* const* d_in, const int* in_sizes, int n_in,
                              void* d_out, int out_size, void* d_ws, size_t ws_size,
                              hipStream_t stream)
{
    const float* x    = (const float*)d_in[0];
    const float* w_t1 = (const float*)d_in[1];
    const float* g_t1 = (const float*)d_in[2];
    const float* b_t1 = (const float*)d_in[3];
    const float* w_t2 = (const float*)d_in[4];
    const float* g_t2 = (const float*)d_in[5];
    const float* b_t2 = (const float*)d_in[6];
    const float* w_nb = (const float*)d_in[7];
    const float* g_nb = (const float*)d_in[8];
    const float* b_nb = (const float*)d_in[9];
    const float* w_s1 = (const float*)d_in[10];
    const float* g_s1 = (const float*)d_in[11];
    const float* b_s1 = (const float*)d_in[12];
    const float* w_s2 = (const float*)d_in[13];
    const float* b_s2 = (const float*)d_in[14];
    float* out = (float*)d_out;

    float* sqA = (float*)d_ws;
    float* sqB = sqA + (size_t)Bn * Nn;
    short* hSa = (short*)(sqB + (size_t)Bn * Nn);
    short* hSb = hSa + 3 * PLN;
    short* wS  = hSb + 3 * PLN;            // 18 planes x 4096 shorts

    k_prep<<<64, 256, 0, stream>>>(w_nb, w_t2, w_s1, wS);
    k_t12<<<Bn * Nn / 16, 256, 0, stream>>>(x, w_t1, g_t1, b_t1,
                                            wS + (size_t)12 * 4096, g_t2, b_t2,
                                            hSa, sqA);

    const short* hSin = hSa;  short* hSout = hSb;
    const float* sqin = sqA;  float* sqo   = sqB;
    for (int r = 0; r < Rr; ++r) {
        k_knn_edge<<<Bn * (Nn / 16), 256, 0, stream>>>(hSin, sqin,
            wS + (size_t)r * 6 * 4096, g_nb + r * Hh, b_nb + r * Hh,
            hSout, sqo);
        const short* ts = hSout; hSout = (short*)hSin; hSin = ts;
        const float* tq = sqo;   sqo   = (float*)sqin; sqin = tq;
    }
    k_head<<<Bn * Nn / 16, 256, 0, stream>>>(hSin, wS + (size_t)15 * 4096,
                                             g_s1, b_s1, w_s2, b_s2, out);
}